// Round 13
// baseline (221.764 us; speedup 1.0000x reference)
//
#include <hip/hip_runtime.h>
#include <hip/hip_bf16.h>
#include <cstdint>

// ---------------------------------------------------------------------------
// Binarized CNN. Verified numerics (R5-R12 passed bit-exact):
//  - binarize(x) == sign(x) exactly; layers 2-4 are exact small-int math in
//    any order -> any packing / instruction choice is safe.
//  - conv1: each accumulator chain MUST sum in (ky,kx,ic)-ascending order
//    (Eigen/XLA-CPU im2col). Chains are independent; fma == mul+add here
//    (weights are +-1/0 so products are exact). DO NOT reorder WITHIN a chain.
//  - k2/k3/k4: MFMA v_mfma_i32_32x32x32_i8 per-tap GEMM (k4: K=32 full).
//  - R13: k1 packs TWO OUTPUT CHANNELS per v_pk_fma_f32 (acc={oc2o,oc2o+1}),
//    weights prepacked {w,w'} -> SGPR pair, window scalar broadcast via
//    op_sel from non-overlapping pairs P[ic][r][j]={col2j,col2j+1}.
//    4 independent chains/iter, no per-iter repacking.
// ---------------------------------------------------------------------------

typedef __attribute__((ext_vector_type(2)))  float f32x2;
typedef __attribute__((ext_vector_type(4)))  int int4v;
typedef __attribute__((ext_vector_type(16))) int int16v;

#define WOFF_W2M 0          // int[9*64*4] = 9216 B (MFMA B-frag table L2)
#define WOFF_W3M 10240      // int[9*64*4] = 9216 B (MFMA B-frag table L3)
#define WOFF_W4M 20480      // int[9*64*4] = 9216 B (MFMA B-frag table L4)
#define WOFF_W1D 30720      // f32x2[108]  =  864 B ({w2o,w2o+1} pairs, k1)
#define WEIGHTS_BYTES 32768

#define A1_PB (2*256*256*4)     // bytes per batch (packed u32, 4 ch/dword)
#define A2_PB (4*254*254*4)
#define A3_PB (8*252*252*4)

__device__ __forceinline__ int fsign(float w) {
    return (w > 0.f) ? 1 : ((w < 0.f) ? -1 : 0);
}

// acc.lo += w.lo * v.lo ; acc.hi += w.hi * v.lo   (broadcast LOW of src1)
__device__ __forceinline__ void pkfma_lo(f32x2& acc, f32x2 w, f32x2 v) {
    asm("v_pk_fma_f32 %0, %1, %2, %0 op_sel:[0,0,0] op_sel_hi:[1,0,1]"
        : "+v"(acc) : "s"(w), "v"(v));
}
// acc.lo += w.lo * v.hi ; acc.hi += w.hi * v.hi   (broadcast HIGH of src1)
__device__ __forceinline__ void pkfma_hi(f32x2& acc, f32x2 w, f32x2 v) {
    asm("v_pk_fma_f32 %0, %1, %2, %0 op_sel:[0,1,0] op_sel_hi:[1,1,1]"
        : "+v"(acc) : "s"(w), "v"(v));
}

// ---- weight prep: 3 blocks (one per table group) -------------------------
__global__ __launch_bounds__(256) void kprep(const float* __restrict__ w1,
                                             const float* __restrict__ w2,
                                             const float* __restrict__ w3,
                                             const float* __restrict__ w4,
                                             int* __restrict__ w2m,
                                             int* __restrict__ w3m,
                                             int* __restrict__ w4m,
                                             f32x2* __restrict__ w1d) {
    int tid = threadIdx.x;
    int b = blockIdx.x;
    if (b == 0) {
        for (int idx = tid; idx < 576; idx += 256) {
            int t = idx / 64, l = idx % 64;
            int oc = l & 31, icb = (l >> 5) * 16;
            int wd[4] = {0, 0, 0, 0};
            for (int j = 0; j < 16; ++j) {
                int ic = icb + j;
                int s = (oc < 16 && ic < 8) ? fsign(w2[(oc * 8 + ic) * 9 + t]) : 0;
                wd[j >> 2] |= (s & 0xff) << (8 * (j & 3));
            }
            w2m[idx * 4 + 0] = wd[0]; w2m[idx * 4 + 1] = wd[1];
            w2m[idx * 4 + 2] = wd[2]; w2m[idx * 4 + 3] = wd[3];
        }
    } else if (b == 1) {
        for (int idx = tid; idx < 576; idx += 256) {
            int t = idx / 64, l = idx % 64;
            int oc = l & 31, icb = (l >> 5) * 16;
            int wd[4] = {0, 0, 0, 0};
            for (int j = 0; j < 16; ++j) {
                int ic = icb + j;
                int s = (ic < 16) ? fsign(w3[(oc * 16 + ic) * 9 + t]) : 0;
                wd[j >> 2] |= (s & 0xff) << (8 * (j & 3));
            }
            w3m[idx * 4 + 0] = wd[0]; w3m[idx * 4 + 1] = wd[1];
            w3m[idx * 4 + 2] = wd[2]; w3m[idx * 4 + 3] = wd[3];
        }
    } else {
        // L4 MFMA B table: K=32 (all ic valid), only oc 0,1 nonzero
        for (int idx = tid; idx < 576; idx += 256) {
            int t = idx / 64, l = idx % 64;
            int oc = l & 31, icb = (l >> 5) * 16;
            int wd[4] = {0, 0, 0, 0};
            for (int j = 0; j < 16; ++j) {
                int ic = icb + j;
                int s = (oc < 2) ? fsign(w4[(oc * 32 + ic) * 9 + t]) : 0;
                wd[j >> 2] |= (s & 0xff) << (8 * (j & 3));
            }
            w4m[idx * 4 + 0] = wd[0]; w4m[idx * 4 + 1] = wd[1];
            w4m[idx * 4 + 2] = wd[2]; w4m[idx * 4 + 3] = wd[3];
        }
        // k1 weight pairs: w1d[op*27 + t] = {sign(w1[2op][t]), sign(w1[2op+1][t])}
        for (int i = tid; i < 108; i += 256) {
            int op = i / 27, t = i % 27;
            float wa = w1[(2 * op) * 27 + t];
            float wbv = w1[(2 * op + 1) * 27 + t];
            f32x2 pr;
            pr[0] = (wa > 0.f) ? 1.f : ((wa < 0.f) ? -1.f : 0.f);
            pr[1] = (wbv > 0.f) ? 1.f : ((wbv < 0.f) ? -1.f : 0.f);
            w1d[i] = pr;
        }
    }
}

// ---- layer 1: pad(1)+conv(3->8)+hardtanh+maxpool2+sign, packed out -------
// R13: oc-paired pk_fma with op_sel broadcast. Each chain (position, oc)
// sums taps in strict (ky,kx,ic)-ascending order: BIT-EXACT per contract.
__global__ __launch_bounds__(256, 4) void k1(const float* __restrict__ x,
                                             const f32x2* __restrict__ w1d,
                                             uint32_t* __restrict__ a1, int n0) {
    int ox = threadIdx.x;   // 0..255
    int oy = blockIdx.y;    // 0..255
    int ln = blockIdx.z;
    const float* xn = x + (size_t)(n0 + ln) * 3 * 512 * 512;

    // window as NON-overlapping column pairs: P[ic][r][j] = {col 2j, col 2j+1}
    f32x2 P[3][4][2];
    int iy0 = 2 * oy - 1, ix0 = 2 * ox - 1;

    if (oy > 0 && oy < 255 && ox > 0 && ox < 255) {
#pragma unroll
        for (int ic = 0; ic < 3; ++ic) {
            const float* xc = xn + (size_t)ic * 512 * 512;
#pragma unroll
            for (int r = 0; r < 4; ++r) {
                const float* rp = xc + (size_t)(iy0 + r) * 512 + ix0;
                float a = rp[0];
                float2 m = *(const float2*)(rp + 1);   // cols 1,2 (aligned)
                float b = rp[3];
                P[ic][r][0] = (f32x2){a, m.x};
                P[ic][r][1] = (f32x2){m.y, b};
            }
        }
    } else {
        for (int ic = 0; ic < 3; ++ic) {
            const float* xc = xn + (size_t)ic * 512 * 512;
#pragma unroll
            for (int r = 0; r < 4; ++r) {
                int iy = iy0 + r;
                bool yok = ((unsigned)iy < 512u);
                float t[4];
#pragma unroll
                for (int c = 0; c < 4; ++c) {
                    int ix = ix0 + c;
                    t[c] = (yok && ((unsigned)ix < 512u))
                               ? xc[(size_t)iy * 512 + ix] : 1.0f;
                }
                P[ic][r][0] = (f32x2){t[0], t[1]};
                P[ic][r][1] = (f32x2){t[2], t[3]};
            }
        }
    }

#define PKTAP(ACC, ROW, COL)                                         \
    do {                                                             \
        if (((COL) & 1) == 0) pkfma_lo(ACC, ww, P[ic][ROW][(COL) >> 1]); \
        else                  pkfma_hi(ACC, ww, P[ic][ROW][(COL) >> 1]); \
    } while (0)

    uint64_t dall = 0;
#pragma unroll 1
    for (int op = 0; op < 4; ++op) {
        f32x2 a00 = {0.f, 0.f}, a01 = {0.f, 0.f};
        f32x2 a10 = {0.f, 0.f}, a11 = {0.f, 0.f};
        const f32x2* wb = w1d + op * 27;
#pragma unroll
        for (int ky = 0; ky < 3; ++ky) {
#pragma unroll
            for (int kx = 0; kx < 3; ++kx) {
#pragma unroll
                for (int ic = 0; ic < 3; ++ic) {
                    f32x2 ww = wb[ic * 9 + ky * 3 + kx];
                    PKTAP(a00, ky + 0, kx + 0);
                    PKTAP(a01, ky + 0, kx + 1);
                    PKTAP(a10, ky + 1, kx + 0);
                    PKTAP(a11, ky + 1, kx + 1);
                }
            }
        }
        float m0 = fmaxf(fmaxf(a00[0], a01[0]), fmaxf(a10[0], a11[0]));
        float m1 = fmaxf(fmaxf(a00[1], a01[1]), fmaxf(a10[1], a11[1]));
        int s0 = (m0 > 0.f) ? 1 : ((m0 < 0.f) ? -1 : 0);
        int s1 = (m1 > 0.f) ? 1 : ((m1 < 0.f) ? -1 : 0);
        dall |= (uint64_t)(uint32_t)(s0 & 0xff) << (8 * (2 * op));
        dall |= (uint64_t)(uint32_t)(s1 & 0xff) << (8 * (2 * op + 1));
    }
#undef PKTAP

    uint32_t d0 = (uint32_t)dall;
    uint32_t d1 = (uint32_t)(dall >> 32);
    size_t base = (((size_t)ln * 2) * 256 + oy) * 256 + ox;
    a1[base]             = d0;
    a1[base + 256 * 256] = d1;
}

// ---- layers 2/3: ternary conv via MFMA i32_32x32x32_i8 -------------------
template<int ICG, int INW, int OUTW, int OCGO>
__global__ __launch_bounds__(256) void kconv(const uint32_t* __restrict__ ain,
                                             const int* __restrict__ wm,
                                             uint32_t* __restrict__ aout) {
    __shared__ uint32_t st[4][3][36][4];   // [wave][row][x][icg] staged acts
    __shared__ uint32_t ep[4][32][9];      // [wave][x][ocg] epilogue repack
    int w    = threadIdx.x >> 6;
    int lane = threadIdx.x & 63;
    int x0 = blockIdx.x * 32;
    int y  = blockIdx.y * 4 + w;
    int ln = blockIdx.z;

    const int4v* wmv = (const int4v*)wm;
    int4v bfr[9];
#pragma unroll
    for (int t = 0; t < 9; ++t) bfr[t] = wmv[t * 64 + lane];

    const uint32_t* abase = ain + (size_t)ln * ICG * INW * INW;
    for (int idx = lane; idx < 432; idx += 64) {
        int icg = idx & 3, tmp = idx >> 2;
        int xx = tmp % 36, row = tmp / 36;
        int gy = y + row, gx = x0 + xx;
        uint32_t val = 0;
        if (icg < ICG && xx < 34 && gx < INW && gy < INW)
            val = abase[((size_t)icg * INW + gy) * INW + gx];
        st[w][row][xx][icg] = val;
    }

    int16v acc = {};
    int xl = lane & 31;
#pragma unroll
    for (int ky = 0; ky < 3; ++ky) {
#pragma unroll
        for (int kx = 0; kx < 3; ++kx) {
            int4v a = *(const int4v*)&st[w][ky][xl + kx][0];
            acc = __builtin_amdgcn_mfma_i32_32x32x32_i8(a, bfr[ky * 3 + kx], acc, 0, 0, 0);
        }
    }

    signed char* epb = (signed char*)&ep[w][0][0];
    int oc = lane & 31;
#pragma unroll
    for (int r = 0; r < 16; ++r) {
        int m = (r & 3) + 8 * (r >> 2) + 4 * (lane >> 5);
        int val = min(max(acc[r], -1), 1);
        epb[m * 36 + oc] = (signed char)val;
    }
    if (y < OUTW && x0 + xl < OUTW) {
#pragma unroll
        for (int it = 0; it < 4; ++it) {
            int ocg = (lane >> 5) * 4 + it;
            if (ocg < OCGO)
                aout[(((size_t)ln * OCGO + ocg) * OUTW + y) * OUTW + x0 + xl] =
                    ep[w][xl][ocg];
        }
    }
}

// ---- layer 4: conv(32->2) via MFMA, K=32 full, f32 out -------------------
__global__ __launch_bounds__(256) void k4m(const uint32_t* __restrict__ a3,
                                           const int* __restrict__ wm,
                                           float* __restrict__ out, int n0) {
    __shared__ uint32_t st[4][3][36][8];   // [wave][row][x][icg]
    __shared__ float ep[4][32][2];         // [wave][px][oc]
    int w    = threadIdx.x >> 6;
    int lane = threadIdx.x & 63;
    int x0 = blockIdx.x * 32;
    int y  = blockIdx.y * 4 + w;
    int ln = blockIdx.z;

    const int4v* wmv = (const int4v*)wm;
    int4v bfr[9];
#pragma unroll
    for (int t = 0; t < 9; ++t) bfr[t] = wmv[t * 64 + lane];

    const uint32_t* abase = a3 + (size_t)ln * 8 * 252 * 252;
    for (int idx = lane; idx < 864; idx += 64) {
        int icg = idx & 7, tmp = idx >> 3;
        int xx = tmp % 36, row = tmp / 36;
        int gy = y + row, gx = x0 + xx;
        uint32_t val = 0;
        if (xx < 34 && gx < 252 && gy < 252)
            val = abase[((size_t)icg * 252 + gy) * 252 + gx];
        st[w][row][xx][icg] = val;
    }

    int16v acc = {};
    int xl = lane & 31;
#pragma unroll
    for (int ky = 0; ky < 3; ++ky) {
#pragma unroll
        for (int kx = 0; kx < 3; ++kx) {
            // lanes 0-31: K bytes 0-15 = icg 0-3; lanes 32-63: icg 4-7
            int4v a = *(const int4v*)&st[w][ky][xl + kx][(lane >> 5) * 4];
            acc = __builtin_amdgcn_mfma_i32_32x32x32_i8(a, bfr[ky * 3 + kx], acc, 0, 0, 0);
        }
    }

    int oc = lane & 31;
    if (oc < 2) {
#pragma unroll
        for (int r = 0; r < 16; ++r) {
            int m = (r & 3) + 8 * (r >> 2) + 4 * (lane >> 5);
            ep[w][m][oc] = fminf(fmaxf((float)acc[r], -1.f), 1.f);
        }
    }
    int px = lane & 31, o = lane >> 5;
    if (y < 250 && x0 + px < 250) {
        size_t gn = (size_t)(n0 + ln);
        out[((gn * 2 + o) * 250 + y) * 250 + (x0 + px)] = ep[w][px][o];
    }
}

extern "C" void kernel_launch(void* const* d_in, const int* in_sizes, int n_in,
                              void* d_out, int out_size, void* d_ws, size_t ws_size,
                              hipStream_t stream) {
    const float* x  = (const float*)d_in[0];
    const float* w1 = (const float*)d_in[1];
    const float* w2 = (const float*)d_in[2];
    const float* w3 = (const float*)d_in[3];
    const float* w4 = (const float*)d_in[4];
    char* ws = (char*)d_ws;

    int*   w2m = (int*)(ws + WOFF_W2M);
    int*   w3m = (int*)(ws + WOFF_W3M);
    int*   w4m = (int*)(ws + WOFF_W4M);
    f32x2* w1d = (f32x2*)(ws + WOFF_W1D);
    float* out = (float*)d_out;

    size_t per = (size_t)A1_PB + (size_t)A2_PB + (size_t)A3_PB;
    int NC = 32;
    while (NC > 1 && (size_t)WEIGHTS_BYTES + (size_t)NC * per > ws_size) NC >>= 1;

    uint32_t* A1 = (uint32_t*)(ws + WEIGHTS_BYTES);
    uint32_t* A2 = (uint32_t*)(ws + WEIGHTS_BYTES + (size_t)NC * A1_PB);
    uint32_t* A3 = (uint32_t*)(ws + WEIGHTS_BYTES + (size_t)NC * (A1_PB + A2_PB));

    kprep<<<dim3(3), 256, 0, stream>>>(w1, w2, w3, w4, w2m, w3m, w4m, w1d);
    for (int n0 = 0; n0 < 32; n0 += NC) {
        k1<<<dim3(1, 256, NC), 256, 0, stream>>>(x, w1d, A1, n0);
        kconv<2, 256, 254, 4><<<dim3(8, 64, NC), 256, 0, stream>>>(A1, w2m, A2);
        kconv<4, 254, 252, 8><<<dim3(8, 63, NC), 256, 0, stream>>>(A2, w3m, A3);
        k4m<<<dim3(8, 63, NC), 256, 0, stream>>>(A3, w4m, out, n0);
    }
}

// Round 14
// 173.144 us; speedup vs baseline: 1.2808x; 1.2808x over previous
//
#include <hip/hip_runtime.h>
#include <hip/hip_bf16.h>
#include <cstdint>

// ---------------------------------------------------------------------------
// Binarized CNN. Verified numerics (R5-R13 passed bit-exact):
//  - binarize(x) == sign(x) exactly; layers 2-4 are exact small-int math in
//    any order -> any packing / instruction choice is safe.
//  - conv1: each accumulator chain MUST sum in (ky,kx,ic)-ascending order
//    (Eigen/XLA-CPU im2col). Chains are independent; fma == mul+add here
//    (weights are +-1/0 so products are exact). DO NOT reorder WITHIN a chain.
//  - k2/k3: MFMA v_mfma_i32_32x32x32_i8 per-tap GEMM (R9, verified layout).
//  - k1: oc-paired v_pk_fma_f32 with op_sel broadcast (R13, verified).
//  - R14: k4 REVERTED to dot4 2x2 (R13's k4m MFMA had 2.45M LDS bank
//    conflicts + duplicated per-wave staging -> 80us; dot4 was ~18us).
// ---------------------------------------------------------------------------

typedef __attribute__((ext_vector_type(2)))  float f32x2;
typedef __attribute__((ext_vector_type(4)))  int int4v;
typedef __attribute__((ext_vector_type(16))) int int16v;

#define WOFF_W2M 0          // int[9*64*4] = 9216 B (MFMA B-frag table L2)
#define WOFF_W3M 10240      // int[9*64*4] = 9216 B (MFMA B-frag table L3)
#define WOFF_W4P 20480      // int[2*8*9]  =  576 B (dot4 packs L4)
#define WOFF_W1D 28672      // f32x2[108]  =  864 B ({w2o,w2o+1} pairs, k1)
#define WEIGHTS_BYTES 32768

#define A1_PB (2*256*256*4)     // bytes per batch (packed u32, 4 ch/dword)
#define A2_PB (4*254*254*4)
#define A3_PB (8*252*252*4)

__device__ __forceinline__ int dot4(int a, int b, int c) {
#if __has_builtin(__builtin_amdgcn_sdot4)
    return __builtin_amdgcn_sdot4(a, b, c, false);
#else
    int s = c;
#pragma unroll
    for (int j = 0; j < 4; ++j) {
        int av = (a << (24 - 8 * j)) >> 24;
        int bv = (b << (24 - 8 * j)) >> 24;
        s += av * bv;
    }
    return s;
#endif
}

__device__ __forceinline__ int fsign(float w) {
    return (w > 0.f) ? 1 : ((w < 0.f) ? -1 : 0);
}

// acc.lo += w.lo * v.lo ; acc.hi += w.hi * v.lo   (broadcast LOW of src1)
__device__ __forceinline__ void pkfma_lo(f32x2& acc, f32x2 w, f32x2 v) {
    asm("v_pk_fma_f32 %0, %1, %2, %0 op_sel:[0,0,0] op_sel_hi:[1,0,1]"
        : "+v"(acc) : "s"(w), "v"(v));
}
// acc.lo += w.lo * v.hi ; acc.hi += w.hi * v.hi   (broadcast HIGH of src1)
__device__ __forceinline__ void pkfma_hi(f32x2& acc, f32x2 w, f32x2 v) {
    asm("v_pk_fma_f32 %0, %1, %2, %0 op_sel:[0,1,0] op_sel_hi:[1,1,1]"
        : "+v"(acc) : "s"(w), "v"(v));
}

// ---- weight prep: 3 blocks (one per table group) -------------------------
__global__ __launch_bounds__(256) void kprep(const float* __restrict__ w1,
                                             const float* __restrict__ w2,
                                             const float* __restrict__ w3,
                                             const float* __restrict__ w4,
                                             int* __restrict__ w2m,
                                             int* __restrict__ w3m,
                                             int* __restrict__ w4p,
                                             f32x2* __restrict__ w1d) {
    int tid = threadIdx.x;
    int b = blockIdx.x;
    if (b == 0) {
        for (int idx = tid; idx < 576; idx += 256) {
            int t = idx / 64, l = idx % 64;
            int oc = l & 31, icb = (l >> 5) * 16;
            int wd[4] = {0, 0, 0, 0};
            for (int j = 0; j < 16; ++j) {
                int ic = icb + j;
                int s = (oc < 16 && ic < 8) ? fsign(w2[(oc * 8 + ic) * 9 + t]) : 0;
                wd[j >> 2] |= (s & 0xff) << (8 * (j & 3));
            }
            w2m[idx * 4 + 0] = wd[0]; w2m[idx * 4 + 1] = wd[1];
            w2m[idx * 4 + 2] = wd[2]; w2m[idx * 4 + 3] = wd[3];
        }
    } else if (b == 1) {
        for (int idx = tid; idx < 576; idx += 256) {
            int t = idx / 64, l = idx % 64;
            int oc = l & 31, icb = (l >> 5) * 16;
            int wd[4] = {0, 0, 0, 0};
            for (int j = 0; j < 16; ++j) {
                int ic = icb + j;
                int s = (ic < 16) ? fsign(w3[(oc * 16 + ic) * 9 + t]) : 0;
                wd[j >> 2] |= (s & 0xff) << (8 * (j & 3));
            }
            w3m[idx * 4 + 0] = wd[0]; w3m[idx * 4 + 1] = wd[1];
            w3m[idx * 4 + 2] = wd[2]; w3m[idx * 4 + 3] = wd[3];
        }
    } else {
        // L4 dot4 packs: w4p[(oc*8+icg)*9+k] byte j = sign(w4[(oc*32+icg*4+j)*9+k])
        for (int idx = tid; idx < 2 * 8 * 9; idx += 256) {
            int k = idx % 9, icg = (idx / 9) % 8, oc = idx / 72;
            int pack = 0;
#pragma unroll
            for (int j = 0; j < 4; ++j)
                pack |= (fsign(w4[(oc * 32 + icg * 4 + j) * 9 + k]) & 0xff) << (8 * j);
            w4p[idx] = pack;
        }
        // k1 weight pairs: w1d[op*27 + t] = {sign(w1[2op][t]), sign(w1[2op+1][t])}
        for (int i = tid; i < 108; i += 256) {
            int op = i / 27, t = i % 27;
            float wa = w1[(2 * op) * 27 + t];
            float wbv = w1[(2 * op + 1) * 27 + t];
            f32x2 pr;
            pr[0] = (wa > 0.f) ? 1.f : ((wa < 0.f) ? -1.f : 0.f);
            pr[1] = (wbv > 0.f) ? 1.f : ((wbv < 0.f) ? -1.f : 0.f);
            w1d[i] = pr;
        }
    }
}

// ---- layer 1: pad(1)+conv(3->8)+hardtanh+maxpool2+sign, packed out -------
// R13: oc-paired pk_fma with op_sel broadcast. Each chain (position, oc)
// sums taps in strict (ky,kx,ic)-ascending order: BIT-EXACT per contract.
__global__ __launch_bounds__(256, 4) void k1(const float* __restrict__ x,
                                             const f32x2* __restrict__ w1d,
                                             uint32_t* __restrict__ a1, int n0) {
    int ox = threadIdx.x;   // 0..255
    int oy = blockIdx.y;    // 0..255
    int ln = blockIdx.z;
    const float* xn = x + (size_t)(n0 + ln) * 3 * 512 * 512;

    // window as NON-overlapping column pairs: P[ic][r][j] = {col 2j, col 2j+1}
    f32x2 P[3][4][2];
    int iy0 = 2 * oy - 1, ix0 = 2 * ox - 1;

    if (oy > 0 && oy < 255 && ox > 0 && ox < 255) {
#pragma unroll
        for (int ic = 0; ic < 3; ++ic) {
            const float* xc = xn + (size_t)ic * 512 * 512;
#pragma unroll
            for (int r = 0; r < 4; ++r) {
                const float* rp = xc + (size_t)(iy0 + r) * 512 + ix0;
                float a = rp[0];
                float2 m = *(const float2*)(rp + 1);   // cols 1,2 (aligned)
                float b = rp[3];
                P[ic][r][0] = (f32x2){a, m.x};
                P[ic][r][1] = (f32x2){m.y, b};
            }
        }
    } else {
        for (int ic = 0; ic < 3; ++ic) {
            const float* xc = xn + (size_t)ic * 512 * 512;
#pragma unroll
            for (int r = 0; r < 4; ++r) {
                int iy = iy0 + r;
                bool yok = ((unsigned)iy < 512u);
                float t[4];
#pragma unroll
                for (int c = 0; c < 4; ++c) {
                    int ix = ix0 + c;
                    t[c] = (yok && ((unsigned)ix < 512u))
                               ? xc[(size_t)iy * 512 + ix] : 1.0f;
                }
                P[ic][r][0] = (f32x2){t[0], t[1]};
                P[ic][r][1] = (f32x2){t[2], t[3]};
            }
        }
    }

#define PKTAP(ACC, ROW, COL)                                         \
    do {                                                             \
        if (((COL) & 1) == 0) pkfma_lo(ACC, ww, P[ic][ROW][(COL) >> 1]); \
        else                  pkfma_hi(ACC, ww, P[ic][ROW][(COL) >> 1]); \
    } while (0)

    uint64_t dall = 0;
#pragma unroll 1
    for (int op = 0; op < 4; ++op) {
        f32x2 a00 = {0.f, 0.f}, a01 = {0.f, 0.f};
        f32x2 a10 = {0.f, 0.f}, a11 = {0.f, 0.f};
        const f32x2* wb = w1d + op * 27;
#pragma unroll
        for (int ky = 0; ky < 3; ++ky) {
#pragma unroll
            for (int kx = 0; kx < 3; ++kx) {
#pragma unroll
                for (int ic = 0; ic < 3; ++ic) {
                    f32x2 ww = wb[ic * 9 + ky * 3 + kx];
                    PKTAP(a00, ky + 0, kx + 0);
                    PKTAP(a01, ky + 0, kx + 1);
                    PKTAP(a10, ky + 1, kx + 0);
                    PKTAP(a11, ky + 1, kx + 1);
                }
            }
        }
        float m0 = fmaxf(fmaxf(a00[0], a01[0]), fmaxf(a10[0], a11[0]));
        float m1 = fmaxf(fmaxf(a00[1], a01[1]), fmaxf(a10[1], a11[1]));
        int s0 = (m0 > 0.f) ? 1 : ((m0 < 0.f) ? -1 : 0);
        int s1 = (m1 > 0.f) ? 1 : ((m1 < 0.f) ? -1 : 0);
        dall |= (uint64_t)(uint32_t)(s0 & 0xff) << (8 * (2 * op));
        dall |= (uint64_t)(uint32_t)(s1 & 0xff) << (8 * (2 * op + 1));
    }
#undef PKTAP

    uint32_t d0 = (uint32_t)dall;
    uint32_t d1 = (uint32_t)(dall >> 32);
    size_t base = (((size_t)ln * 2) * 256 + oy) * 256 + ox;
    a1[base]             = d0;
    a1[base + 256 * 256] = d1;
}

// ---- layers 2/3: ternary conv via MFMA i32_32x32x32_i8 -------------------
template<int ICG, int INW, int OUTW, int OCGO>
__global__ __launch_bounds__(256) void kconv(const uint32_t* __restrict__ ain,
                                             const int* __restrict__ wm,
                                             uint32_t* __restrict__ aout) {
    __shared__ uint32_t st[4][3][36][4];   // [wave][row][x][icg] staged acts
    __shared__ uint32_t ep[4][32][9];      // [wave][x][ocg] epilogue repack
    int w    = threadIdx.x >> 6;
    int lane = threadIdx.x & 63;
    int x0 = blockIdx.x * 32;
    int y  = blockIdx.y * 4 + w;
    int ln = blockIdx.z;

    const int4v* wmv = (const int4v*)wm;
    int4v bfr[9];
#pragma unroll
    for (int t = 0; t < 9; ++t) bfr[t] = wmv[t * 64 + lane];

    const uint32_t* abase = ain + (size_t)ln * ICG * INW * INW;
    for (int idx = lane; idx < 432; idx += 64) {
        int icg = idx & 3, tmp = idx >> 2;
        int xx = tmp % 36, row = tmp / 36;
        int gy = y + row, gx = x0 + xx;
        uint32_t val = 0;
        if (icg < ICG && xx < 34 && gx < INW && gy < INW)
            val = abase[((size_t)icg * INW + gy) * INW + gx];
        st[w][row][xx][icg] = val;
    }

    int16v acc = {};
    int xl = lane & 31;
#pragma unroll
    for (int ky = 0; ky < 3; ++ky) {
#pragma unroll
        for (int kx = 0; kx < 3; ++kx) {
            int4v a = *(const int4v*)&st[w][ky][xl + kx][0];
            acc = __builtin_amdgcn_mfma_i32_32x32x32_i8(a, bfr[ky * 3 + kx], acc, 0, 0, 0);
        }
    }

    signed char* epb = (signed char*)&ep[w][0][0];
    int oc = lane & 31;
#pragma unroll
    for (int r = 0; r < 16; ++r) {
        int m = (r & 3) + 8 * (r >> 2) + 4 * (lane >> 5);
        int val = min(max(acc[r], -1), 1);
        epb[m * 36 + oc] = (signed char)val;
    }
    if (y < OUTW && x0 + xl < OUTW) {
#pragma unroll
        for (int it = 0; it < 4; ++it) {
            int ocg = (lane >> 5) * 4 + it;
            if (ocg < OCGO)
                aout[(((size_t)ln * OCGO + ocg) * OUTW + y) * OUTW + x0 + xl] =
                    ep[w][xl][ocg];
        }
    }
}

// ---- layer 4: conv(32->2) ternary, dot4, 2x2 outputs/thread, f32 out -----
__global__ __launch_bounds__(128) void k4(const uint32_t* __restrict__ a3,
                                          const int* __restrict__ w4p,
                                          float* __restrict__ out, int n0) {
    int ox = threadIdx.x; if (ox >= 125) return;
    int oy0 = blockIdx.y * 2;
    int ln = blockIdx.z;

    int acc[2][2][2] = {};
#pragma unroll
    for (int icg = 0; icg < 8; ++icg) {
        uint32_t r[4][4];
        const uint32_t* base = a3 + (((size_t)ln * 8 + icg) * 252 + oy0) * 252 + 2 * ox;
#pragma unroll
        for (int j = 0; j < 4; ++j) {
            uint2 lo = *(const uint2*)(base + (size_t)j * 252);
            uint2 hi = *(const uint2*)(base + (size_t)j * 252 + 2);
            r[j][0] = lo.x; r[j][1] = lo.y; r[j][2] = hi.x; r[j][3] = hi.y;
        }
#pragma unroll
        for (int o = 0; o < 2; ++o) {
            const int* wb = w4p + ((o * 8 + icg) * 9);
#pragma unroll
            for (int ky = 0; ky < 3; ++ky) {
#pragma unroll
                for (int p = 0; p < 2; ++p) {
#pragma unroll
                    for (int q = 0; q < 2; ++q) {
                        acc[p][q][o] = dot4((int)r[p + ky][q + 0], wb[ky * 3 + 0], acc[p][q][o]);
                        acc[p][q][o] = dot4((int)r[p + ky][q + 1], wb[ky * 3 + 1], acc[p][q][o]);
                        acc[p][q][o] = dot4((int)r[p + ky][q + 2], wb[ky * 3 + 2], acc[p][q][o]);
                    }
                }
            }
        }
    }
    size_t gn = (size_t)(n0 + ln);
#pragma unroll
    for (int o = 0; o < 2; ++o)
#pragma unroll
        for (int p = 0; p < 2; ++p) {
            float2 w;
            w.x = fminf(fmaxf((float)acc[p][0][o], -1.f), 1.f);
            w.y = fminf(fmaxf((float)acc[p][1][o], -1.f), 1.f);
            *(float2*)(out + ((gn * 2 + o) * 250 + (oy0 + p)) * 250 + 2 * ox) = w;
        }
}

extern "C" void kernel_launch(void* const* d_in, const int* in_sizes, int n_in,
                              void* d_out, int out_size, void* d_ws, size_t ws_size,
                              hipStream_t stream) {
    const float* x  = (const float*)d_in[0];
    const float* w1 = (const float*)d_in[1];
    const float* w2 = (const float*)d_in[2];
    const float* w3 = (const float*)d_in[3];
    const float* w4 = (const float*)d_in[4];
    char* ws = (char*)d_ws;

    int*   w2m = (int*)(ws + WOFF_W2M);
    int*   w3m = (int*)(ws + WOFF_W3M);
    int*   w4p = (int*)(ws + WOFF_W4P);
    f32x2* w1d = (f32x2*)(ws + WOFF_W1D);
    float* out = (float*)d_out;

    size_t per = (size_t)A1_PB + (size_t)A2_PB + (size_t)A3_PB;
    int NC = 32;
    while (NC > 1 && (size_t)WEIGHTS_BYTES + (size_t)NC * per > ws_size) NC >>= 1;

    uint32_t* A1 = (uint32_t*)(ws + WEIGHTS_BYTES);
    uint32_t* A2 = (uint32_t*)(ws + WEIGHTS_BYTES + (size_t)NC * A1_PB);
    uint32_t* A3 = (uint32_t*)(ws + WEIGHTS_BYTES + (size_t)NC * (A1_PB + A2_PB));

    kprep<<<dim3(3), 256, 0, stream>>>(w1, w2, w3, w4, w2m, w3m, w4p, w1d);
    for (int n0 = 0; n0 < 32; n0 += NC) {
        k1<<<dim3(1, 256, NC), 256, 0, stream>>>(x, w1d, A1, n0);
        kconv<2, 256, 254, 4><<<dim3(8, 64, NC), 256, 0, stream>>>(A1, w2m, A2);
        kconv<4, 254, 252, 8><<<dim3(8, 63, NC), 256, 0, stream>>>(A2, w3m, A3);
        k4<<<dim3(1, 125, NC), 128, 0, stream>>>(A3, w4p, out, n0);
    }
}

// Round 15
// 153.722 us; speedup vs baseline: 1.4426x; 1.1263x over previous
//
#include <hip/hip_runtime.h>
#include <hip/hip_bf16.h>
#include <cstdint>

// ---------------------------------------------------------------------------
// Binarized CNN. Verified numerics (R5-R14 passed bit-exact):
//  - binarize(x) == sign(x) exactly; layers 2-4 are exact small-int math in
//    any order -> any packing / instruction choice is safe.
//  - conv1: each accumulator chain MUST sum in (ky,kx,ic)-ascending order
//    (Eigen/XLA-CPU im2col). Chains independent; fma == mul+add (w in +-1/0).
//    DO NOT reorder WITHIN a chain. Pad value 1.0.
//  - k2/k3: MFMA v_mfma_i32_32x32x32_i8 per-tap GEMM (R9 layout, verified).
//  - k4: dot4 2x2 (R12, verified). k1 acc: oc-paired pk_fma (R13, verified).
//  - R15: (a) k1 window via LDS stage (pads baked in, no divergent border
//    path) + asm pins to stop global-remat; (b) kconv block-cooperative
//    6-row staging (one shared buffer + barrier instead of 4 private).
// ---------------------------------------------------------------------------

typedef __attribute__((ext_vector_type(2)))  float f32x2;
typedef __attribute__((ext_vector_type(4)))  int int4v;
typedef __attribute__((ext_vector_type(16))) int int16v;

#define WOFF_W2M 0          // int[9*64*4] = 9216 B (MFMA B-frag table L2)
#define WOFF_W3M 10240      // int[9*64*4] = 9216 B (MFMA B-frag table L3)
#define WOFF_W4P 20480      // int[2*8*9]  =  576 B (dot4 packs L4)
#define WOFF_W1D 28672      // f32x2[108]  =  864 B ({w2o,w2o+1} pairs, k1)
#define WEIGHTS_BYTES 32768

#define A1_PB (2*256*256*4)     // bytes per batch (packed u32, 4 ch/dword)
#define A2_PB (4*254*254*4)
#define A3_PB (8*252*252*4)

__device__ __forceinline__ int dot4(int a, int b, int c) {
#if __has_builtin(__builtin_amdgcn_sdot4)
    return __builtin_amdgcn_sdot4(a, b, c, false);
#else
    int s = c;
#pragma unroll
    for (int j = 0; j < 4; ++j) {
        int av = (a << (24 - 8 * j)) >> 24;
        int bv = (b << (24 - 8 * j)) >> 24;
        s += av * bv;
    }
    return s;
#endif
}

__device__ __forceinline__ int fsign(float w) {
    return (w > 0.f) ? 1 : ((w < 0.f) ? -1 : 0);
}

// acc.lo += w.lo * v.lo ; acc.hi += w.hi * v.lo   (broadcast LOW of src1)
__device__ __forceinline__ void pkfma_lo(f32x2& acc, f32x2 w, f32x2 v) {
    asm("v_pk_fma_f32 %0, %1, %2, %0 op_sel:[0,0,0] op_sel_hi:[1,0,1]"
        : "+v"(acc) : "s"(w), "v"(v));
}
// acc.lo += w.lo * v.hi ; acc.hi += w.hi * v.hi   (broadcast HIGH of src1)
__device__ __forceinline__ void pkfma_hi(f32x2& acc, f32x2 w, f32x2 v) {
    asm("v_pk_fma_f32 %0, %1, %2, %0 op_sel:[0,1,0] op_sel_hi:[1,1,1]"
        : "+v"(acc) : "s"(w), "v"(v));
}

// ---- weight prep: 3 blocks (one per table group) -------------------------
__global__ __launch_bounds__(256) void kprep(const float* __restrict__ w1,
                                             const float* __restrict__ w2,
                                             const float* __restrict__ w3,
                                             const float* __restrict__ w4,
                                             int* __restrict__ w2m,
                                             int* __restrict__ w3m,
                                             int* __restrict__ w4p,
                                             f32x2* __restrict__ w1d) {
    int tid = threadIdx.x;
    int b = blockIdx.x;
    if (b == 0) {
        for (int idx = tid; idx < 576; idx += 256) {
            int t = idx / 64, l = idx % 64;
            int oc = l & 31, icb = (l >> 5) * 16;
            int wd[4] = {0, 0, 0, 0};
            for (int j = 0; j < 16; ++j) {
                int ic = icb + j;
                int s = (oc < 16 && ic < 8) ? fsign(w2[(oc * 8 + ic) * 9 + t]) : 0;
                wd[j >> 2] |= (s & 0xff) << (8 * (j & 3));
            }
            w2m[idx * 4 + 0] = wd[0]; w2m[idx * 4 + 1] = wd[1];
            w2m[idx * 4 + 2] = wd[2]; w2m[idx * 4 + 3] = wd[3];
        }
    } else if (b == 1) {
        for (int idx = tid; idx < 576; idx += 256) {
            int t = idx / 64, l = idx % 64;
            int oc = l & 31, icb = (l >> 5) * 16;
            int wd[4] = {0, 0, 0, 0};
            for (int j = 0; j < 16; ++j) {
                int ic = icb + j;
                int s = (ic < 16) ? fsign(w3[(oc * 16 + ic) * 9 + t]) : 0;
                wd[j >> 2] |= (s & 0xff) << (8 * (j & 3));
            }
            w3m[idx * 4 + 0] = wd[0]; w3m[idx * 4 + 1] = wd[1];
            w3m[idx * 4 + 2] = wd[2]; w3m[idx * 4 + 3] = wd[3];
        }
    } else {
        for (int idx = tid; idx < 2 * 8 * 9; idx += 256) {
            int k = idx % 9, icg = (idx / 9) % 8, oc = idx / 72;
            int pack = 0;
#pragma unroll
            for (int j = 0; j < 4; ++j)
                pack |= (fsign(w4[(oc * 32 + icg * 4 + j) * 9 + k]) & 0xff) << (8 * j);
            w4p[idx] = pack;
        }
        for (int i = tid; i < 108; i += 256) {
            int op = i / 27, t = i % 27;
            float wa = w1[(2 * op) * 27 + t];
            float wbv = w1[(2 * op + 1) * 27 + t];
            f32x2 pr;
            pr[0] = (wa > 0.f) ? 1.f : ((wa < 0.f) ? -1.f : 0.f);
            pr[1] = (wbv > 0.f) ? 1.f : ((wbv < 0.f) ? -1.f : 0.f);
            w1d[i] = pr;
        }
    }
}

// ---- layer 1: pad(1)+conv(3->8)+hardtanh+maxpool2+sign, packed out -------
// R15: window staged in LDS (col c <-> input x = c-1; pads = 1.0 baked in),
// P pairs read as aligned b64, pinned into VGPRs. Accumulation chains
// unchanged from R13 (verified): strict (ky,kx,ic)-ascending per chain.
__global__ __launch_bounds__(256, 4) void k1(const float* __restrict__ x,
                                             const f32x2* __restrict__ w1d,
                                             uint32_t* __restrict__ a1, int n0) {
    __shared__ float xsh[3][4][520];   // [ic][r][col], col c <-> x = c-1
    int ox = threadIdx.x;   // 0..255
    int oy = blockIdx.y;    // 0..255
    int ln = blockIdx.z;
    const float* xn = x + (size_t)(n0 + ln) * 3 * 512 * 512;
    int iy0 = 2 * oy - 1;

    // cooperative stage: 3 ic x 4 rows x 128 float4 groups (cols 1..512)
    for (int idx = threadIdx.x; idx < 1536; idx += 256) {
        int j = idx & 127, tmp = idx >> 7;
        int r = tmp & 3, ic = tmp >> 2;
        int iy = iy0 + r;
        float4 vv;
        if ((unsigned)iy < 512u)
            vv = *(const float4*)(xn + (size_t)ic * 512 * 512 + (size_t)iy * 512 + 4 * j);
        else
            vv = float4{1.f, 1.f, 1.f, 1.f};
        xsh[ic][r][4 * j + 1] = vv.x;
        xsh[ic][r][4 * j + 2] = vv.y;
        xsh[ic][r][4 * j + 3] = vv.z;
        xsh[ic][r][4 * j + 4] = vv.w;
    }
    if (threadIdx.x < 12) {
        int r = threadIdx.x & 3, ic = threadIdx.x >> 2;
        xsh[ic][r][0]   = 1.f;    // x = -1 pad (or invalid row: 1.0 either way)
        xsh[ic][r][513] = 1.f;    // x = 512 pad
    }
    __syncthreads();

    // P[ic][r][j] = {x[2ox-1+2j], x[2ox+2j]} == lds cols {2ox+2j, 2ox+2j+1}
    f32x2 P[3][4][2];
#pragma unroll
    for (int ic = 0; ic < 3; ++ic)
#pragma unroll
        for (int r = 0; r < 4; ++r) {
            P[ic][r][0] = *(const f32x2*)&xsh[ic][r][2 * ox];
            P[ic][r][1] = *(const f32x2*)&xsh[ic][r][2 * ox + 2];
        }
    // pin window in VGPRs (values become asm outputs -> no remat of loads)
#pragma unroll
    for (int ic = 0; ic < 3; ++ic)
#pragma unroll
        for (int r = 0; r < 4; ++r)
#pragma unroll
            for (int j = 0; j < 2; ++j)
                asm volatile("" : "+v"(P[ic][r][j]));

#define PKTAP(ACC, ROW, COL)                                         \
    do {                                                             \
        if (((COL) & 1) == 0) pkfma_lo(ACC, ww, P[ic][ROW][(COL) >> 1]); \
        else                  pkfma_hi(ACC, ww, P[ic][ROW][(COL) >> 1]); \
    } while (0)

    uint64_t dall = 0;
#pragma unroll 1
    for (int op = 0; op < 4; ++op) {
        f32x2 a00 = {0.f, 0.f}, a01 = {0.f, 0.f};
        f32x2 a10 = {0.f, 0.f}, a11 = {0.f, 0.f};
        const f32x2* wb = w1d + op * 27;
#pragma unroll
        for (int ky = 0; ky < 3; ++ky) {
#pragma unroll
            for (int kx = 0; kx < 3; ++kx) {
#pragma unroll
                for (int ic = 0; ic < 3; ++ic) {
                    f32x2 ww = wb[ic * 9 + ky * 3 + kx];
                    PKTAP(a00, ky + 0, kx + 0);
                    PKTAP(a01, ky + 0, kx + 1);
                    PKTAP(a10, ky + 1, kx + 0);
                    PKTAP(a11, ky + 1, kx + 1);
                }
            }
        }
        float m0 = fmaxf(fmaxf(a00[0], a01[0]), fmaxf(a10[0], a11[0]));
        float m1 = fmaxf(fmaxf(a00[1], a01[1]), fmaxf(a10[1], a11[1]));
        int s0 = (m0 > 0.f) ? 1 : ((m0 < 0.f) ? -1 : 0);
        int s1 = (m1 > 0.f) ? 1 : ((m1 < 0.f) ? -1 : 0);
        dall |= (uint64_t)(uint32_t)(s0 & 0xff) << (8 * (2 * op));
        dall |= (uint64_t)(uint32_t)(s1 & 0xff) << (8 * (2 * op + 1));
    }
#undef PKTAP

    uint32_t d0 = (uint32_t)dall;
    uint32_t d1 = (uint32_t)(dall >> 32);
    size_t base = (((size_t)ln * 2) * 256 + oy) * 256 + ox;
    a1[base]             = d0;
    a1[base + 256 * 256] = d1;
}

// ---- layers 2/3: ternary conv via MFMA i32_32x32x32_i8 -------------------
// R15: block-cooperative staging — 6 rows shared by the 4 waves (was 4x3
// private rows with 2x duplication). A-fragment layout/reads unchanged.
template<int ICG, int INW, int OUTW, int OCGO>
__global__ __launch_bounds__(256) void kconv(const uint32_t* __restrict__ ain,
                                             const int* __restrict__ wm,
                                             uint32_t* __restrict__ aout) {
    __shared__ uint32_t stb[6][36][4];     // [row][x][icg], rows y0..y0+5
    __shared__ uint32_t ep[4][32][9];      // [wave][x][ocg] epilogue repack
    int w    = threadIdx.x >> 6;
    int lane = threadIdx.x & 63;
    int x0 = blockIdx.x * 32;
    int y0 = blockIdx.y * 4;
    int y  = y0 + w;
    int ln = blockIdx.z;

    const int4v* wmv = (const int4v*)wm;
    int4v bfr[9];
#pragma unroll
    for (int t = 0; t < 9; ++t) bfr[t] = wmv[t * 64 + lane];

    const uint32_t* abase = ain + (size_t)ln * ICG * INW * INW;
    for (int idx = threadIdx.x; idx < 6 * 36 * 4; idx += 256) {
        int xx = idx % 36, tmp = idx / 36;
        int icg = tmp & 3, row = tmp >> 2;
        int gy = y0 + row, gx = x0 + xx;
        uint32_t val = 0;
        if (icg < ICG && xx < 34 && gx < INW && gy < INW)
            val = abase[((size_t)icg * INW + gy) * INW + gx];
        stb[row][xx][icg] = val;
    }
    __syncthreads();

    int16v acc = {};
    int xl = lane & 31;
#pragma unroll
    for (int ky = 0; ky < 3; ++ky) {
#pragma unroll
        for (int kx = 0; kx < 3; ++kx) {
            int4v a = *(const int4v*)&stb[w + ky][xl + kx][0];
            acc = __builtin_amdgcn_mfma_i32_32x32x32_i8(a, bfr[ky * 3 + kx], acc, 0, 0, 0);
        }
    }

    signed char* epb = (signed char*)&ep[w][0][0];
    int oc = lane & 31;
#pragma unroll
    for (int r = 0; r < 16; ++r) {
        int m = (r & 3) + 8 * (r >> 2) + 4 * (lane >> 5);
        int val = min(max(acc[r], -1), 1);
        epb[m * 36 + oc] = (signed char)val;
    }
    if (y < OUTW && x0 + xl < OUTW) {
#pragma unroll
        for (int it = 0; it < 4; ++it) {
            int ocg = (lane >> 5) * 4 + it;
            if (ocg < OCGO)
                aout[(((size_t)ln * OCGO + ocg) * OUTW + y) * OUTW + x0 + xl] =
                    ep[w][xl][ocg];
        }
    }
}

// ---- layer 4: conv(32->2) ternary, dot4, 2x2 outputs/thread, f32 out -----
__global__ __launch_bounds__(128) void k4(const uint32_t* __restrict__ a3,
                                          const int* __restrict__ w4p,
                                          float* __restrict__ out, int n0) {
    int ox = threadIdx.x; if (ox >= 125) return;
    int oy0 = blockIdx.y * 2;
    int ln = blockIdx.z;

    int acc[2][2][2] = {};
#pragma unroll
    for (int icg = 0; icg < 8; ++icg) {
        uint32_t r[4][4];
        const uint32_t* base = a3 + (((size_t)ln * 8 + icg) * 252 + oy0) * 252 + 2 * ox;
#pragma unroll
        for (int j = 0; j < 4; ++j) {
            uint2 lo = *(const uint2*)(base + (size_t)j * 252);
            uint2 hi = *(const uint2*)(base + (size_t)j * 252 + 2);
            r[j][0] = lo.x; r[j][1] = lo.y; r[j][2] = hi.x; r[j][3] = hi.y;
        }
#pragma unroll
        for (int o = 0; o < 2; ++o) {
            const int* wb = w4p + ((o * 8 + icg) * 9);
#pragma unroll
            for (int ky = 0; ky < 3; ++ky) {
#pragma unroll
                for (int p = 0; p < 2; ++p) {
#pragma unroll
                    for (int q = 0; q < 2; ++q) {
                        acc[p][q][o] = dot4((int)r[p + ky][q + 0], wb[ky * 3 + 0], acc[p][q][o]);
                        acc[p][q][o] = dot4((int)r[p + ky][q + 1], wb[ky * 3 + 1], acc[p][q][o]);
                        acc[p][q][o] = dot4((int)r[p + ky][q + 2], wb[ky * 3 + 2], acc[p][q][o]);
                    }
                }
            }
        }
    }
    size_t gn = (size_t)(n0 + ln);
#pragma unroll
    for (int o = 0; o < 2; ++o)
#pragma unroll
        for (int p = 0; p < 2; ++p) {
            float2 w;
            w.x = fminf(fmaxf((float)acc[p][0][o], -1.f), 1.f);
            w.y = fminf(fmaxf((float)acc[p][1][o], -1.f), 1.f);
            *(float2*)(out + ((gn * 2 + o) * 250 + (oy0 + p)) * 250 + 2 * ox) = w;
        }
}

extern "C" void kernel_launch(void* const* d_in, const int* in_sizes, int n_in,
                              void* d_out, int out_size, void* d_ws, size_t ws_size,
                              hipStream_t stream) {
    const float* x  = (const float*)d_in[0];
    const float* w1 = (const float*)d_in[1];
    const float* w2 = (const float*)d_in[2];
    const float* w3 = (const float*)d_in[3];
    const float* w4 = (const float*)d_in[4];
    char* ws = (char*)d_ws;

    int*   w2m = (int*)(ws + WOFF_W2M);
    int*   w3m = (int*)(ws + WOFF_W3M);
    int*   w4p = (int*)(ws + WOFF_W4P);
    f32x2* w1d = (f32x2*)(ws + WOFF_W1D);
    float* out = (float*)d_out;

    size_t per = (size_t)A1_PB + (size_t)A2_PB + (size_t)A3_PB;
    int NC = 32;
    while (NC > 1 && (size_t)WEIGHTS_BYTES + (size_t)NC * per > ws_size) NC >>= 1;

    uint32_t* A1 = (uint32_t*)(ws + WEIGHTS_BYTES);
    uint32_t* A2 = (uint32_t*)(ws + WEIGHTS_BYTES + (size_t)NC * A1_PB);
    uint32_t* A3 = (uint32_t*)(ws + WEIGHTS_BYTES + (size_t)NC * (A1_PB + A2_PB));

    kprep<<<dim3(3), 256, 0, stream>>>(w1, w2, w3, w4, w2m, w3m, w4p, w1d);
    for (int n0 = 0; n0 < 32; n0 += NC) {
        k1<<<dim3(1, 256, NC), 256, 0, stream>>>(x, w1d, A1, n0);
        kconv<2, 256, 254, 4><<<dim3(8, 64, NC), 256, 0, stream>>>(A1, w2m, A2);
        kconv<4, 254, 252, 8><<<dim3(8, 63, NC), 256, 0, stream>>>(A2, w3m, A3);
        k4<<<dim3(1, 125, NC), 128, 0, stream>>>(A3, w4p, out, n0);
    }
}

// Round 16
// 147.840 us; speedup vs baseline: 1.5000x; 1.0398x over previous
//
#include <hip/hip_runtime.h>
#include <hip/hip_bf16.h>
#include <cstdint>

// ---------------------------------------------------------------------------
// Binarized CNN. Verified numerics (R5-R15 passed bit-exact):
//  - binarize(x) == sign(x) exactly; layers 2-4 are exact small-int math in
//    any order -> any packing / instruction choice is safe.
//  - conv1: each accumulator chain MUST sum in (ky,kx,ic)-ascending order
//    (Eigen/XLA-CPU im2col). Chains independent; fma == mul+add (w in +-1/0).
//    DO NOT reorder WITHIN a chain. Pad value 1.0.
//  - k2/k3: MFMA v_mfma_i32_32x32x32_i8 per-tap GEMM (R9 layout, verified).
//  - k4: dot4 2x2 (R12, verified). k1: R13/R14 global-load pk_fma version
//    (59.4us, 0 LDS conflicts — R15's LDS-staged k1 regressed: 4.75M
//    bank conflicts from the +1-shifted layout; reverted).
//  - R16: kconv row-tile R=8 (2 rows/wave, 18 MFMA) amortizes per-block
//    fixed costs 2x; stage only real ICG planes (uninit icg>=ICG dwords
//    hit zero B-bytes -> contribute exactly 0).
// ---------------------------------------------------------------------------

typedef __attribute__((ext_vector_type(2)))  float f32x2;
typedef __attribute__((ext_vector_type(4)))  int int4v;
typedef __attribute__((ext_vector_type(16))) int int16v;

#define WOFF_W2M 0          // int[9*64*4] = 9216 B (MFMA B-frag table L2)
#define WOFF_W3M 10240      // int[9*64*4] = 9216 B (MFMA B-frag table L3)
#define WOFF_W4P 20480      // int[2*8*9]  =  576 B (dot4 packs L4)
#define WOFF_W1D 28672      // f32x2[108]  =  864 B ({w2o,w2o+1} pairs, k1)
#define WEIGHTS_BYTES 32768

#define A1_PB (2*256*256*4)     // bytes per batch (packed u32, 4 ch/dword)
#define A2_PB (4*254*254*4)
#define A3_PB (8*252*252*4)

__device__ __forceinline__ int dot4(int a, int b, int c) {
#if __has_builtin(__builtin_amdgcn_sdot4)
    return __builtin_amdgcn_sdot4(a, b, c, false);
#else
    int s = c;
#pragma unroll
    for (int j = 0; j < 4; ++j) {
        int av = (a << (24 - 8 * j)) >> 24;
        int bv = (b << (24 - 8 * j)) >> 24;
        s += av * bv;
    }
    return s;
#endif
}

__device__ __forceinline__ int fsign(float w) {
    return (w > 0.f) ? 1 : ((w < 0.f) ? -1 : 0);
}

// acc.lo += w.lo * v.lo ; acc.hi += w.hi * v.lo   (broadcast LOW of src1)
__device__ __forceinline__ void pkfma_lo(f32x2& acc, f32x2 w, f32x2 v) {
    asm("v_pk_fma_f32 %0, %1, %2, %0 op_sel:[0,0,0] op_sel_hi:[1,0,1]"
        : "+v"(acc) : "s"(w), "v"(v));
}
// acc.lo += w.lo * v.hi ; acc.hi += w.hi * v.hi   (broadcast HIGH of src1)
__device__ __forceinline__ void pkfma_hi(f32x2& acc, f32x2 w, f32x2 v) {
    asm("v_pk_fma_f32 %0, %1, %2, %0 op_sel:[0,1,0] op_sel_hi:[1,1,1]"
        : "+v"(acc) : "s"(w), "v"(v));
}

// ---- weight prep: 3 blocks (one per table group) -------------------------
__global__ __launch_bounds__(256) void kprep(const float* __restrict__ w1,
                                             const float* __restrict__ w2,
                                             const float* __restrict__ w3,
                                             const float* __restrict__ w4,
                                             int* __restrict__ w2m,
                                             int* __restrict__ w3m,
                                             int* __restrict__ w4p,
                                             f32x2* __restrict__ w1d) {
    int tid = threadIdx.x;
    int b = blockIdx.x;
    if (b == 0) {
        for (int idx = tid; idx < 576; idx += 256) {
            int t = idx / 64, l = idx % 64;
            int oc = l & 31, icb = (l >> 5) * 16;
            int wd[4] = {0, 0, 0, 0};
            for (int j = 0; j < 16; ++j) {
                int ic = icb + j;
                int s = (oc < 16 && ic < 8) ? fsign(w2[(oc * 8 + ic) * 9 + t]) : 0;
                wd[j >> 2] |= (s & 0xff) << (8 * (j & 3));
            }
            w2m[idx * 4 + 0] = wd[0]; w2m[idx * 4 + 1] = wd[1];
            w2m[idx * 4 + 2] = wd[2]; w2m[idx * 4 + 3] = wd[3];
        }
    } else if (b == 1) {
        for (int idx = tid; idx < 576; idx += 256) {
            int t = idx / 64, l = idx % 64;
            int oc = l & 31, icb = (l >> 5) * 16;
            int wd[4] = {0, 0, 0, 0};
            for (int j = 0; j < 16; ++j) {
                int ic = icb + j;
                int s = (ic < 16) ? fsign(w3[(oc * 16 + ic) * 9 + t]) : 0;
                wd[j >> 2] |= (s & 0xff) << (8 * (j & 3));
            }
            w3m[idx * 4 + 0] = wd[0]; w3m[idx * 4 + 1] = wd[1];
            w3m[idx * 4 + 2] = wd[2]; w3m[idx * 4 + 3] = wd[3];
        }
    } else {
        for (int idx = tid; idx < 2 * 8 * 9; idx += 256) {
            int k = idx % 9, icg = (idx / 9) % 8, oc = idx / 72;
            int pack = 0;
#pragma unroll
            for (int j = 0; j < 4; ++j)
                pack |= (fsign(w4[(oc * 32 + icg * 4 + j) * 9 + k]) & 0xff) << (8 * j);
            w4p[idx] = pack;
        }
        for (int i = tid; i < 108; i += 256) {
            int op = i / 27, t = i % 27;
            float wa = w1[(2 * op) * 27 + t];
            float wbv = w1[(2 * op + 1) * 27 + t];
            f32x2 pr;
            pr[0] = (wa > 0.f) ? 1.f : ((wa < 0.f) ? -1.f : 0.f);
            pr[1] = (wbv > 0.f) ? 1.f : ((wbv < 0.f) ? -1.f : 0.f);
            w1d[i] = pr;
        }
    }
}

// ---- layer 1: pad(1)+conv(3->8)+hardtanh+maxpool2+sign, packed out -------
// R13/R14 version (verified, 59.4us): oc-paired pk_fma with op_sel
// broadcast; global window loads. Chains strict (ky,kx,ic)-ascending.
__global__ __launch_bounds__(256, 4) void k1(const float* __restrict__ x,
                                             const f32x2* __restrict__ w1d,
                                             uint32_t* __restrict__ a1, int n0) {
    int ox = threadIdx.x;   // 0..255
    int oy = blockIdx.y;    // 0..255
    int ln = blockIdx.z;
    const float* xn = x + (size_t)(n0 + ln) * 3 * 512 * 512;

    // window as NON-overlapping column pairs: P[ic][r][j] = {col 2j, col 2j+1}
    f32x2 P[3][4][2];
    int iy0 = 2 * oy - 1, ix0 = 2 * ox - 1;

    if (oy > 0 && oy < 255 && ox > 0 && ox < 255) {
#pragma unroll
        for (int ic = 0; ic < 3; ++ic) {
            const float* xc = xn + (size_t)ic * 512 * 512;
#pragma unroll
            for (int r = 0; r < 4; ++r) {
                const float* rp = xc + (size_t)(iy0 + r) * 512 + ix0;
                float a = rp[0];
                float2 m = *(const float2*)(rp + 1);   // cols 1,2 (aligned)
                float b = rp[3];
                P[ic][r][0] = (f32x2){a, m.x};
                P[ic][r][1] = (f32x2){m.y, b};
            }
        }
    } else {
        for (int ic = 0; ic < 3; ++ic) {
            const float* xc = xn + (size_t)ic * 512 * 512;
#pragma unroll
            for (int r = 0; r < 4; ++r) {
                int iy = iy0 + r;
                bool yok = ((unsigned)iy < 512u);
                float t[4];
#pragma unroll
                for (int c = 0; c < 4; ++c) {
                    int ix = ix0 + c;
                    t[c] = (yok && ((unsigned)ix < 512u))
                               ? xc[(size_t)iy * 512 + ix] : 1.0f;
                }
                P[ic][r][0] = (f32x2){t[0], t[1]};
                P[ic][r][1] = (f32x2){t[2], t[3]};
            }
        }
    }

#define PKTAP(ACC, ROW, COL)                                         \
    do {                                                             \
        if (((COL) & 1) == 0) pkfma_lo(ACC, ww, P[ic][ROW][(COL) >> 1]); \
        else                  pkfma_hi(ACC, ww, P[ic][ROW][(COL) >> 1]); \
    } while (0)

    uint64_t dall = 0;
#pragma unroll 1
    for (int op = 0; op < 4; ++op) {
        f32x2 a00 = {0.f, 0.f}, a01 = {0.f, 0.f};
        f32x2 a10 = {0.f, 0.f}, a11 = {0.f, 0.f};
        const f32x2* wb = w1d + op * 27;
#pragma unroll
        for (int ky = 0; ky < 3; ++ky) {
#pragma unroll
            for (int kx = 0; kx < 3; ++kx) {
#pragma unroll
                for (int ic = 0; ic < 3; ++ic) {
                    f32x2 ww = wb[ic * 9 + ky * 3 + kx];
                    PKTAP(a00, ky + 0, kx + 0);
                    PKTAP(a01, ky + 0, kx + 1);
                    PKTAP(a10, ky + 1, kx + 0);
                    PKTAP(a11, ky + 1, kx + 1);
                }
            }
        }
        float m0 = fmaxf(fmaxf(a00[0], a01[0]), fmaxf(a10[0], a11[0]));
        float m1 = fmaxf(fmaxf(a00[1], a01[1]), fmaxf(a10[1], a11[1]));
        int s0 = (m0 > 0.f) ? 1 : ((m0 < 0.f) ? -1 : 0);
        int s1 = (m1 > 0.f) ? 1 : ((m1 < 0.f) ? -1 : 0);
        dall |= (uint64_t)(uint32_t)(s0 & 0xff) << (8 * (2 * op));
        dall |= (uint64_t)(uint32_t)(s1 & 0xff) << (8 * (2 * op + 1));
    }
#undef PKTAP

    uint32_t d0 = (uint32_t)dall;
    uint32_t d1 = (uint32_t)(dall >> 32);
    size_t base = (((size_t)ln * 2) * 256 + oy) * 256 + ox;
    a1[base]             = d0;
    a1[base + 256 * 256] = d1;
}

// ---- layers 2/3: ternary conv via MFMA i32_32x32x32_i8 -------------------
// R16: 8 output rows per block (2 per wave, 18 MFMA), 10 staged rows.
// Only real ICG planes staged; icg>=ICG A-garbage hits zero B-bytes -> 0.
template<int ICG, int INW, int OUTW, int OCGO>
__global__ __launch_bounds__(256) void kconv(const uint32_t* __restrict__ ain,
                                             const int* __restrict__ wm,
                                             uint32_t* __restrict__ aout) {
    __shared__ uint32_t stb[10][36][4];    // [row][x][icg], rows y0..y0+9
    __shared__ uint32_t ep[4][32][9];      // [wave][x][ocg] epilogue repack
    constexpr int LG = (ICG == 2) ? 1 : 2;
    int w    = threadIdx.x >> 6;
    int lane = threadIdx.x & 63;
    int x0 = blockIdx.x * 32;
    int y0 = blockIdx.y * 8;
    int ln = blockIdx.z;

    const int4v* wmv = (const int4v*)wm;
    int4v bfr[9];
#pragma unroll
    for (int t = 0; t < 9; ++t) bfr[t] = wmv[t * 64 + lane];

    const uint32_t* abase = ain + (size_t)ln * ICG * INW * INW;
    for (int idx = threadIdx.x; idx < 10 * 36 * ICG; idx += 256) {
        int icg = idx & (ICG - 1);
        int r2 = idx >> LG;
        int xx = r2 % 36, row = r2 / 36;
        int gy = y0 + row, gx = x0 + xx;
        uint32_t val = 0;
        if (xx < 34 && gx < INW && gy < INW)
            val = abase[((size_t)icg * INW + gy) * INW + gx];
        stb[row][xx][icg] = val;
    }
    __syncthreads();

    int xl = lane & 31;
    int oc = lane & 31;
    signed char* epb = (signed char*)&ep[w][0][0];

#pragma unroll
    for (int ry = 0; ry < 2; ++ry) {
        int yy = y0 + 2 * w + ry;
        int16v acc = {};
#pragma unroll
        for (int ky = 0; ky < 3; ++ky) {
#pragma unroll
            for (int kx = 0; kx < 3; ++kx) {
                int4v a = *(const int4v*)&stb[2 * w + ry + ky][xl + kx][0];
                acc = __builtin_amdgcn_mfma_i32_32x32x32_i8(a, bfr[ky * 3 + kx], acc, 0, 0, 0);
            }
        }
#pragma unroll
        for (int r = 0; r < 16; ++r) {
            int m = (r & 3) + 8 * (r >> 2) + 4 * (lane >> 5);
            int val = min(max(acc[r], -1), 1);
            epb[m * 36 + oc] = (signed char)val;
        }
        if (yy < OUTW && x0 + xl < OUTW) {
#pragma unroll
            for (int it = 0; it < 4; ++it) {
                int ocg = (lane >> 5) * 4 + it;
                if (ocg < OCGO)
                    aout[(((size_t)ln * OCGO + ocg) * OUTW + yy) * OUTW + x0 + xl] =
                        ep[w][xl][ocg];
            }
        }
    }
}

// ---- layer 4: conv(32->2) ternary, dot4, 2x2 outputs/thread, f32 out -----
__global__ __launch_bounds__(128) void k4(const uint32_t* __restrict__ a3,
                                          const int* __restrict__ w4p,
                                          float* __restrict__ out, int n0) {
    int ox = threadIdx.x; if (ox >= 125) return;
    int oy0 = blockIdx.y * 2;
    int ln = blockIdx.z;

    int acc[2][2][2] = {};
#pragma unroll
    for (int icg = 0; icg < 8; ++icg) {
        uint32_t r[4][4];
        const uint32_t* base = a3 + (((size_t)ln * 8 + icg) * 252 + oy0) * 252 + 2 * ox;
#pragma unroll
        for (int j = 0; j < 4; ++j) {
            uint2 lo = *(const uint2*)(base + (size_t)j * 252);
            uint2 hi = *(const uint2*)(base + (size_t)j * 252 + 2);
            r[j][0] = lo.x; r[j][1] = lo.y; r[j][2] = hi.x; r[j][3] = hi.y;
        }
#pragma unroll
        for (int o = 0; o < 2; ++o) {
            const int* wb = w4p + ((o * 8 + icg) * 9);
#pragma unroll
            for (int ky = 0; ky < 3; ++ky) {
#pragma unroll
                for (int p = 0; p < 2; ++p) {
#pragma unroll
                    for (int q = 0; q < 2; ++q) {
                        acc[p][q][o] = dot4((int)r[p + ky][q + 0], wb[ky * 3 + 0], acc[p][q][o]);
                        acc[p][q][o] = dot4((int)r[p + ky][q + 1], wb[ky * 3 + 1], acc[p][q][o]);
                        acc[p][q][o] = dot4((int)r[p + ky][q + 2], wb[ky * 3 + 2], acc[p][q][o]);
                    }
                }
            }
        }
    }
    size_t gn = (size_t)(n0 + ln);
#pragma unroll
    for (int o = 0; o < 2; ++o)
#pragma unroll
        for (int p = 0; p < 2; ++p) {
            float2 w;
            w.x = fminf(fmaxf((float)acc[p][0][o], -1.f), 1.f);
            w.y = fminf(fmaxf((float)acc[p][1][o], -1.f), 1.f);
            *(float2*)(out + ((gn * 2 + o) * 250 + (oy0 + p)) * 250 + 2 * ox) = w;
        }
}

extern "C" void kernel_launch(void* const* d_in, const int* in_sizes, int n_in,
                              void* d_out, int out_size, void* d_ws, size_t ws_size,
                              hipStream_t stream) {
    const float* x  = (const float*)d_in[0];
    const float* w1 = (const float*)d_in[1];
    const float* w2 = (const float*)d_in[2];
    const float* w3 = (const float*)d_in[3];
    const float* w4 = (const float*)d_in[4];
    char* ws = (char*)d_ws;

    int*   w2m = (int*)(ws + WOFF_W2M);
    int*   w3m = (int*)(ws + WOFF_W3M);
    int*   w4p = (int*)(ws + WOFF_W4P);
    f32x2* w1d = (f32x2*)(ws + WOFF_W1D);
    float* out = (float*)d_out;

    size_t per = (size_t)A1_PB + (size_t)A2_PB + (size_t)A3_PB;
    int NC = 32;
    while (NC > 1 && (size_t)WEIGHTS_BYTES + (size_t)NC * per > ws_size) NC >>= 1;

    uint32_t* A1 = (uint32_t*)(ws + WEIGHTS_BYTES);
    uint32_t* A2 = (uint32_t*)(ws + WEIGHTS_BYTES + (size_t)NC * A1_PB);
    uint32_t* A3 = (uint32_t*)(ws + WEIGHTS_BYTES + (size_t)NC * (A1_PB + A2_PB));

    kprep<<<dim3(3), 256, 0, stream>>>(w1, w2, w3, w4, w2m, w3m, w4p, w1d);
    for (int n0 = 0; n0 < 32; n0 += NC) {
        k1<<<dim3(1, 256, NC), 256, 0, stream>>>(x, w1d, A1, n0);
        kconv<2, 256, 254, 4><<<dim3(8, 32, NC), 256, 0, stream>>>(A1, w2m, A2);
        kconv<4, 254, 252, 8><<<dim3(8, 32, NC), 256, 0, stream>>>(A2, w3m, A3);
        k4<<<dim3(1, 125, NC), 128, 0, stream>>>(A3, w4p, out, n0);
    }
}

// Round 17
// 146.654 us; speedup vs baseline: 1.5122x; 1.0081x over previous
//
#include <hip/hip_runtime.h>
#include <hip/hip_bf16.h>
#include <cstdint>

// ---------------------------------------------------------------------------
// Binarized CNN. Verified numerics (R5-R16 passed bit-exact):
//  - binarize(x) == sign(x) exactly; layers 2-4 are exact small-int math in
//    any order -> any packing / instruction choice is safe.
//  - conv1: each accumulator chain MUST sum in (ky,kx,ic)-ascending order
//    (Eigen/XLA-CPU im2col). Chains independent; fma == mul+add (w in +-1/0).
//    DO NOT reorder WITHIN a chain. Pad value 1.0.
//  - k2/k3: MFMA v_mfma_i32_32x32x32_i8 per-tap GEMM (R9 layout, verified);
//    R16 row-tile R=8 (2 rows/wave).
//  - k4: dot4 2x2 (R12, verified). k1: oc-paired pk_fma (R13, verified).
//  - R17: k1 op-loop FULLY UNROLLED (was #pragma unroll 1, which serialized
//    4 phases of {27 scalar weight loads -> 108 pk_fma on 4 chains}; full
//    unroll lets the compiler pipeline weight loads under math and
//    interleave up to 16 independent chains). Unrolling does not reorder
//    any chain -> bit-exact.
// ---------------------------------------------------------------------------

typedef __attribute__((ext_vector_type(2)))  float f32x2;
typedef __attribute__((ext_vector_type(4)))  int int4v;
typedef __attribute__((ext_vector_type(16))) int int16v;

#define WOFF_W2M 0          // int[9*64*4] = 9216 B (MFMA B-frag table L2)
#define WOFF_W3M 10240      // int[9*64*4] = 9216 B (MFMA B-frag table L3)
#define WOFF_W4P 20480      // int[2*8*9]  =  576 B (dot4 packs L4)
#define WOFF_W1D 28672      // f32x2[108]  =  864 B ({w2o,w2o+1} pairs, k1)
#define WEIGHTS_BYTES 32768

#define A1_PB (2*256*256*4)     // bytes per batch (packed u32, 4 ch/dword)
#define A2_PB (4*254*254*4)
#define A3_PB (8*252*252*4)

__device__ __forceinline__ int dot4(int a, int b, int c) {
#if __has_builtin(__builtin_amdgcn_sdot4)
    return __builtin_amdgcn_sdot4(a, b, c, false);
#else
    int s = c;
#pragma unroll
    for (int j = 0; j < 4; ++j) {
        int av = (a << (24 - 8 * j)) >> 24;
        int bv = (b << (24 - 8 * j)) >> 24;
        s += av * bv;
    }
    return s;
#endif
}

__device__ __forceinline__ int fsign(float w) {
    return (w > 0.f) ? 1 : ((w < 0.f) ? -1 : 0);
}

// acc.lo += w.lo * v.lo ; acc.hi += w.hi * v.lo   (broadcast LOW of src1)
__device__ __forceinline__ void pkfma_lo(f32x2& acc, f32x2 w, f32x2 v) {
    asm("v_pk_fma_f32 %0, %1, %2, %0 op_sel:[0,0,0] op_sel_hi:[1,0,1]"
        : "+v"(acc) : "s"(w), "v"(v));
}
// acc.lo += w.lo * v.hi ; acc.hi += w.hi * v.hi   (broadcast HIGH of src1)
__device__ __forceinline__ void pkfma_hi(f32x2& acc, f32x2 w, f32x2 v) {
    asm("v_pk_fma_f32 %0, %1, %2, %0 op_sel:[0,1,0] op_sel_hi:[1,1,1]"
        : "+v"(acc) : "s"(w), "v"(v));
}

// ---- weight prep: 3 blocks (one per table group) -------------------------
__global__ __launch_bounds__(256) void kprep(const float* __restrict__ w1,
                                             const float* __restrict__ w2,
                                             const float* __restrict__ w3,
                                             const float* __restrict__ w4,
                                             int* __restrict__ w2m,
                                             int* __restrict__ w3m,
                                             int* __restrict__ w4p,
                                             f32x2* __restrict__ w1d) {
    int tid = threadIdx.x;
    int b = blockIdx.x;
    if (b == 0) {
        for (int idx = tid; idx < 576; idx += 256) {
            int t = idx / 64, l = idx % 64;
            int oc = l & 31, icb = (l >> 5) * 16;
            int wd[4] = {0, 0, 0, 0};
            for (int j = 0; j < 16; ++j) {
                int ic = icb + j;
                int s = (oc < 16 && ic < 8) ? fsign(w2[(oc * 8 + ic) * 9 + t]) : 0;
                wd[j >> 2] |= (s & 0xff) << (8 * (j & 3));
            }
            w2m[idx * 4 + 0] = wd[0]; w2m[idx * 4 + 1] = wd[1];
            w2m[idx * 4 + 2] = wd[2]; w2m[idx * 4 + 3] = wd[3];
        }
    } else if (b == 1) {
        for (int idx = tid; idx < 576; idx += 256) {
            int t = idx / 64, l = idx % 64;
            int oc = l & 31, icb = (l >> 5) * 16;
            int wd[4] = {0, 0, 0, 0};
            for (int j = 0; j < 16; ++j) {
                int ic = icb + j;
                int s = (ic < 16) ? fsign(w3[(oc * 16 + ic) * 9 + t]) : 0;
                wd[j >> 2] |= (s & 0xff) << (8 * (j & 3));
            }
            w3m[idx * 4 + 0] = wd[0]; w3m[idx * 4 + 1] = wd[1];
            w3m[idx * 4 + 2] = wd[2]; w3m[idx * 4 + 3] = wd[3];
        }
    } else {
        for (int idx = tid; idx < 2 * 8 * 9; idx += 256) {
            int k = idx % 9, icg = (idx / 9) % 8, oc = idx / 72;
            int pack = 0;
#pragma unroll
            for (int j = 0; j < 4; ++j)
                pack |= (fsign(w4[(oc * 32 + icg * 4 + j) * 9 + k]) & 0xff) << (8 * j);
            w4p[idx] = pack;
        }
        for (int i = tid; i < 108; i += 256) {
            int op = i / 27, t = i % 27;
            float wa = w1[(2 * op) * 27 + t];
            float wbv = w1[(2 * op + 1) * 27 + t];
            f32x2 pr;
            pr[0] = (wa > 0.f) ? 1.f : ((wa < 0.f) ? -1.f : 0.f);
            pr[1] = (wbv > 0.f) ? 1.f : ((wbv < 0.f) ? -1.f : 0.f);
            w1d[i] = pr;
        }
    }
}

// ---- layer 1: pad(1)+conv(3->8)+hardtanh+maxpool2+sign, packed out -------
// R17: op loop fully unrolled. Chains strict (ky,kx,ic)-ascending (verified).
__global__ __launch_bounds__(256, 4) void k1(const float* __restrict__ x,
                                             const f32x2* __restrict__ w1d,
                                             uint32_t* __restrict__ a1, int n0) {
    int ox = threadIdx.x;   // 0..255
    int oy = blockIdx.y;    // 0..255
    int ln = blockIdx.z;
    const float* xn = x + (size_t)(n0 + ln) * 3 * 512 * 512;

    // window as NON-overlapping column pairs: P[ic][r][j] = {col 2j, col 2j+1}
    f32x2 P[3][4][2];
    int iy0 = 2 * oy - 1, ix0 = 2 * ox - 1;

    if (oy > 0 && oy < 255 && ox > 0 && ox < 255) {
#pragma unroll
        for (int ic = 0; ic < 3; ++ic) {
            const float* xc = xn + (size_t)ic * 512 * 512;
#pragma unroll
            for (int r = 0; r < 4; ++r) {
                const float* rp = xc + (size_t)(iy0 + r) * 512 + ix0;
                float a = rp[0];
                float2 m = *(const float2*)(rp + 1);   // cols 1,2 (aligned)
                float b = rp[3];
                P[ic][r][0] = (f32x2){a, m.x};
                P[ic][r][1] = (f32x2){m.y, b};
            }
        }
    } else {
        for (int ic = 0; ic < 3; ++ic) {
            const float* xc = xn + (size_t)ic * 512 * 512;
#pragma unroll
            for (int r = 0; r < 4; ++r) {
                int iy = iy0 + r;
                bool yok = ((unsigned)iy < 512u);
                float t[4];
#pragma unroll
                for (int c = 0; c < 4; ++c) {
                    int ix = ix0 + c;
                    t[c] = (yok && ((unsigned)ix < 512u))
                               ? xc[(size_t)iy * 512 + ix] : 1.0f;
                }
                P[ic][r][0] = (f32x2){t[0], t[1]};
                P[ic][r][1] = (f32x2){t[2], t[3]};
            }
        }
    }

#define PKTAP(ACC, ROW, COL)                                         \
    do {                                                             \
        if (((COL) & 1) == 0) pkfma_lo(ACC, ww, P[ic][ROW][(COL) >> 1]); \
        else                  pkfma_hi(ACC, ww, P[ic][ROW][(COL) >> 1]); \
    } while (0)

    uint64_t dall = 0;
#pragma unroll
    for (int op = 0; op < 4; ++op) {
        f32x2 a00 = {0.f, 0.f}, a01 = {0.f, 0.f};
        f32x2 a10 = {0.f, 0.f}, a11 = {0.f, 0.f};
        const f32x2* wb = w1d + op * 27;
#pragma unroll
        for (int ky = 0; ky < 3; ++ky) {
#pragma unroll
            for (int kx = 0; kx < 3; ++kx) {
#pragma unroll
                for (int ic = 0; ic < 3; ++ic) {
                    f32x2 ww = wb[ic * 9 + ky * 3 + kx];
                    PKTAP(a00, ky + 0, kx + 0);
                    PKTAP(a01, ky + 0, kx + 1);
                    PKTAP(a10, ky + 1, kx + 0);
                    PKTAP(a11, ky + 1, kx + 1);
                }
            }
        }
        float m0 = fmaxf(fmaxf(a00[0], a01[0]), fmaxf(a10[0], a11[0]));
        float m1 = fmaxf(fmaxf(a00[1], a01[1]), fmaxf(a10[1], a11[1]));
        int s0 = (m0 > 0.f) ? 1 : ((m0 < 0.f) ? -1 : 0);
        int s1 = (m1 > 0.f) ? 1 : ((m1 < 0.f) ? -1 : 0);
        dall |= (uint64_t)(uint32_t)(s0 & 0xff) << (8 * (2 * op));
        dall |= (uint64_t)(uint32_t)(s1 & 0xff) << (8 * (2 * op + 1));
    }
#undef PKTAP

    uint32_t d0 = (uint32_t)dall;
    uint32_t d1 = (uint32_t)(dall >> 32);
    size_t base = (((size_t)ln * 2) * 256 + oy) * 256 + ox;
    a1[base]             = d0;
    a1[base + 256 * 256] = d1;
}

// ---- layers 2/3: ternary conv via MFMA i32_32x32x32_i8 -------------------
// R16: 8 output rows per block (2 per wave, 18 MFMA), 10 staged rows.
template<int ICG, int INW, int OUTW, int OCGO>
__global__ __launch_bounds__(256) void kconv(const uint32_t* __restrict__ ain,
                                             const int* __restrict__ wm,
                                             uint32_t* __restrict__ aout) {
    __shared__ uint32_t stb[10][36][4];    // [row][x][icg], rows y0..y0+9
    __shared__ uint32_t ep[4][32][9];      // [wave][x][ocg] epilogue repack
    constexpr int LG = (ICG == 2) ? 1 : 2;
    int w    = threadIdx.x >> 6;
    int lane = threadIdx.x & 63;
    int x0 = blockIdx.x * 32;
    int y0 = blockIdx.y * 8;
    int ln = blockIdx.z;

    const int4v* wmv = (const int4v*)wm;
    int4v bfr[9];
#pragma unroll
    for (int t = 0; t < 9; ++t) bfr[t] = wmv[t * 64 + lane];

    const uint32_t* abase = ain + (size_t)ln * ICG * INW * INW;
    for (int idx = threadIdx.x; idx < 10 * 36 * ICG; idx += 256) {
        int icg = idx & (ICG - 1);
        int r2 = idx >> LG;
        int xx = r2 % 36, row = r2 / 36;
        int gy = y0 + row, gx = x0 + xx;
        uint32_t val = 0;
        if (xx < 34 && gx < INW && gy < INW)
            val = abase[((size_t)icg * INW + gy) * INW + gx];
        stb[row][xx][icg] = val;
    }
    __syncthreads();

    int xl = lane & 31;
    int oc = lane & 31;
    signed char* epb = (signed char*)&ep[w][0][0];

#pragma unroll
    for (int ry = 0; ry < 2; ++ry) {
        int yy = y0 + 2 * w + ry;
        int16v acc = {};
#pragma unroll
        for (int ky = 0; ky < 3; ++ky) {
#pragma unroll
            for (int kx = 0; kx < 3; ++kx) {
                int4v a = *(const int4v*)&stb[2 * w + ry + ky][xl + kx][0];
                acc = __builtin_amdgcn_mfma_i32_32x32x32_i8(a, bfr[ky * 3 + kx], acc, 0, 0, 0);
            }
        }
#pragma unroll
        for (int r = 0; r < 16; ++r) {
            int m = (r & 3) + 8 * (r >> 2) + 4 * (lane >> 5);
            int val = min(max(acc[r], -1), 1);
            epb[m * 36 + oc] = (signed char)val;
        }
        if (yy < OUTW && x0 + xl < OUTW) {
#pragma unroll
            for (int it = 0; it < 4; ++it) {
                int ocg = (lane >> 5) * 4 + it;
                if (ocg < OCGO)
                    aout[(((size_t)ln * OCGO + ocg) * OUTW + yy) * OUTW + x0 + xl] =
                        ep[w][xl][ocg];
            }
        }
    }
}

// ---- layer 4: conv(32->2) ternary, dot4, 2x2 outputs/thread, f32 out -----
__global__ __launch_bounds__(128) void k4(const uint32_t* __restrict__ a3,
                                          const int* __restrict__ w4p,
                                          float* __restrict__ out, int n0) {
    int ox = threadIdx.x; if (ox >= 125) return;
    int oy0 = blockIdx.y * 2;
    int ln = blockIdx.z;

    int acc[2][2][2] = {};
#pragma unroll
    for (int icg = 0; icg < 8; ++icg) {
        uint32_t r[4][4];
        const uint32_t* base = a3 + (((size_t)ln * 8 + icg) * 252 + oy0) * 252 + 2 * ox;
#pragma unroll
        for (int j = 0; j < 4; ++j) {
            uint2 lo = *(const uint2*)(base + (size_t)j * 252);
            uint2 hi = *(const uint2*)(base + (size_t)j * 252 + 2);
            r[j][0] = lo.x; r[j][1] = lo.y; r[j][2] = hi.x; r[j][3] = hi.y;
        }
#pragma unroll
        for (int o = 0; o < 2; ++o) {
            const int* wb = w4p + ((o * 8 + icg) * 9);
#pragma unroll
            for (int ky = 0; ky < 3; ++ky) {
#pragma unroll
                for (int p = 0; p < 2; ++p) {
#pragma unroll
                    for (int q = 0; q < 2; ++q) {
                        acc[p][q][o] = dot4((int)r[p + ky][q + 0], wb[ky * 3 + 0], acc[p][q][o]);
                        acc[p][q][o] = dot4((int)r[p + ky][q + 1], wb[ky * 3 + 1], acc[p][q][o]);
                        acc[p][q][o] = dot4((int)r[p + ky][q + 2], wb[ky * 3 + 2], acc[p][q][o]);
                    }
                }
            }
        }
    }
    size_t gn = (size_t)(n0 + ln);
#pragma unroll
    for (int o = 0; o < 2; ++o)
#pragma unroll
        for (int p = 0; p < 2; ++p) {
            float2 w;
            w.x = fminf(fmaxf((float)acc[p][0][o], -1.f), 1.f);
            w.y = fminf(fmaxf((float)acc[p][1][o], -1.f), 1.f);
            *(float2*)(out + ((gn * 2 + o) * 250 + (oy0 + p)) * 250 + 2 * ox) = w;
        }
}

extern "C" void kernel_launch(void* const* d_in, const int* in_sizes, int n_in,
                              void* d_out, int out_size, void* d_ws, size_t ws_size,
                              hipStream_t stream) {
    const float* x  = (const float*)d_in[0];
    const float* w1 = (const float*)d_in[1];
    const float* w2 = (const float*)d_in[2];
    const float* w3 = (const float*)d_in[3];
    const float* w4 = (const float*)d_in[4];
    char* ws = (char*)d_ws;

    int*   w2m = (int*)(ws + WOFF_W2M);
    int*   w3m = (int*)(ws + WOFF_W3M);
    int*   w4p = (int*)(ws + WOFF_W4P);
    f32x2* w1d = (f32x2*)(ws + WOFF_W1D);
    float* out = (float*)d_out;

    size_t per = (size_t)A1_PB + (size_t)A2_PB + (size_t)A3_PB;
    int NC = 32;
    while (NC > 1 && (size_t)WEIGHTS_BYTES + (size_t)NC * per > ws_size) NC >>= 1;

    uint32_t* A1 = (uint32_t*)(ws + WEIGHTS_BYTES);
    uint32_t* A2 = (uint32_t*)(ws + WEIGHTS_BYTES + (size_t)NC * A1_PB);
    uint32_t* A3 = (uint32_t*)(ws + WEIGHTS_BYTES + (size_t)NC * (A1_PB + A2_PB));

    kprep<<<dim3(3), 256, 0, stream>>>(w1, w2, w3, w4, w2m, w3m, w4p, w1d);
    for (int n0 = 0; n0 < 32; n0 += NC) {
        k1<<<dim3(1, 256, NC), 256, 0, stream>>>(x, w1d, A1, n0);
        kconv<2, 256, 254, 4><<<dim3(8, 32, NC), 256, 0, stream>>>(A1, w2m, A2);
        kconv<4, 254, 252, 8><<<dim3(8, 32, NC), 256, 0, stream>>>(A2, w3m, A3);
        k4<<<dim3(1, 125, NC), 128, 0, stream>>>(A3, w4p, out, n0);
    }
}

// Round 18
// 146.577 us; speedup vs baseline: 1.5129x; 1.0005x over previous
//
#include <hip/hip_runtime.h>
#include <hip/hip_bf16.h>
#include <cstdint>

// ---------------------------------------------------------------------------
// Binarized CNN. Verified numerics (R5-R17 passed bit-exact):
//  - binarize(x) == sign(x) exactly; layers 2-4 are exact small-int math in
//    any order -> any packing / instruction choice is safe.
//  - conv1: each accumulator chain MUST sum in (ky,kx,ic)-ascending order
//    (Eigen/XLA-CPU im2col). Chains independent; fma == mul+add (w in +-1/0).
//    DO NOT reorder WITHIN a chain. Pad value 1.0.
//  - k2/k3: MFMA v_mfma_i32_32x32x32_i8 per-tap GEMM.
//    R18: OPERAND SWAP — weights as A, activations as B (fragments have
//    identical per-lane layout, so tables/LDS reads unchanged). C[oc,px]:
//    lane=px holds oc=8g+4h+j at reg 4g+j -> pack output dwords in-register,
//    store direct to global. Removes the ep[] LDS byte-epilogue (4-way
//    write conflicts + lgkm stalls) entirely.
//  - k4: dot4 2x2 (R12, verified). k1: oc-paired pk_fma (R13/R17, verified).
// ---------------------------------------------------------------------------

typedef __attribute__((ext_vector_type(2)))  float f32x2;
typedef __attribute__((ext_vector_type(4)))  int int4v;
typedef __attribute__((ext_vector_type(16))) int int16v;

#define WOFF_W2M 0          // int[9*64*4] = 9216 B (MFMA frag table L2)
#define WOFF_W3M 10240      // int[9*64*4] = 9216 B (MFMA frag table L3)
#define WOFF_W4P 20480      // int[2*8*9]  =  576 B (dot4 packs L4)
#define WOFF_W1D 28672      // f32x2[108]  =  864 B ({w2o,w2o+1} pairs, k1)
#define WEIGHTS_BYTES 32768

#define A1_PB (2*256*256*4)     // bytes per batch (packed u32, 4 ch/dword)
#define A2_PB (4*254*254*4)
#define A3_PB (8*252*252*4)

__device__ __forceinline__ int dot4(int a, int b, int c) {
#if __has_builtin(__builtin_amdgcn_sdot4)
    return __builtin_amdgcn_sdot4(a, b, c, false);
#else
    int s = c;
#pragma unroll
    for (int j = 0; j < 4; ++j) {
        int av = (a << (24 - 8 * j)) >> 24;
        int bv = (b << (24 - 8 * j)) >> 24;
        s += av * bv;
    }
    return s;
#endif
}

__device__ __forceinline__ int fsign(float w) {
    return (w > 0.f) ? 1 : ((w < 0.f) ? -1 : 0);
}

// acc.lo += w.lo * v.lo ; acc.hi += w.hi * v.lo   (broadcast LOW of src1)
__device__ __forceinline__ void pkfma_lo(f32x2& acc, f32x2 w, f32x2 v) {
    asm("v_pk_fma_f32 %0, %1, %2, %0 op_sel:[0,0,0] op_sel_hi:[1,0,1]"
        : "+v"(acc) : "s"(w), "v"(v));
}
// acc.lo += w.lo * v.hi ; acc.hi += w.hi * v.hi   (broadcast HIGH of src1)
__device__ __forceinline__ void pkfma_hi(f32x2& acc, f32x2 w, f32x2 v) {
    asm("v_pk_fma_f32 %0, %1, %2, %0 op_sel:[0,1,0] op_sel_hi:[1,1,1]"
        : "+v"(acc) : "s"(w), "v"(v));
}

// ---- weight prep: 3 blocks (one per table group) -------------------------
__global__ __launch_bounds__(256) void kprep(const float* __restrict__ w1,
                                             const float* __restrict__ w2,
                                             const float* __restrict__ w3,
                                             const float* __restrict__ w4,
                                             int* __restrict__ w2m,
                                             int* __restrict__ w3m,
                                             int* __restrict__ w4p,
                                             f32x2* __restrict__ w1d) {
    int tid = threadIdx.x;
    int b = blockIdx.x;
    if (b == 0) {
        for (int idx = tid; idx < 576; idx += 256) {
            int t = idx / 64, l = idx % 64;
            int oc = l & 31, icb = (l >> 5) * 16;
            int wd[4] = {0, 0, 0, 0};
            for (int j = 0; j < 16; ++j) {
                int ic = icb + j;
                int s = (oc < 16 && ic < 8) ? fsign(w2[(oc * 8 + ic) * 9 + t]) : 0;
                wd[j >> 2] |= (s & 0xff) << (8 * (j & 3));
            }
            w2m[idx * 4 + 0] = wd[0]; w2m[idx * 4 + 1] = wd[1];
            w2m[idx * 4 + 2] = wd[2]; w2m[idx * 4 + 3] = wd[3];
        }
    } else if (b == 1) {
        for (int idx = tid; idx < 576; idx += 256) {
            int t = idx / 64, l = idx % 64;
            int oc = l & 31, icb = (l >> 5) * 16;
            int wd[4] = {0, 0, 0, 0};
            for (int j = 0; j < 16; ++j) {
                int ic = icb + j;
                int s = (ic < 16) ? fsign(w3[(oc * 16 + ic) * 9 + t]) : 0;
                wd[j >> 2] |= (s & 0xff) << (8 * (j & 3));
            }
            w3m[idx * 4 + 0] = wd[0]; w3m[idx * 4 + 1] = wd[1];
            w3m[idx * 4 + 2] = wd[2]; w3m[idx * 4 + 3] = wd[3];
        }
    } else {
        for (int idx = tid; idx < 2 * 8 * 9; idx += 256) {
            int k = idx % 9, icg = (idx / 9) % 8, oc = idx / 72;
            int pack = 0;
#pragma unroll
            for (int j = 0; j < 4; ++j)
                pack |= (fsign(w4[(oc * 32 + icg * 4 + j) * 9 + k]) & 0xff) << (8 * j);
            w4p[idx] = pack;
        }
        for (int i = tid; i < 108; i += 256) {
            int op = i / 27, t = i % 27;
            float wa = w1[(2 * op) * 27 + t];
            float wbv = w1[(2 * op + 1) * 27 + t];
            f32x2 pr;
            pr[0] = (wa > 0.f) ? 1.f : ((wa < 0.f) ? -1.f : 0.f);
            pr[1] = (wbv > 0.f) ? 1.f : ((wbv < 0.f) ? -1.f : 0.f);
            w1d[i] = pr;
        }
    }
}

// ---- layer 1: pad(1)+conv(3->8)+hardtanh+maxpool2+sign, packed out -------
// R17 version (verified): oc-paired pk_fma, op loop fully unrolled.
__global__ __launch_bounds__(256, 4) void k1(const float* __restrict__ x,
                                             const f32x2* __restrict__ w1d,
                                             uint32_t* __restrict__ a1, int n0) {
    int ox = threadIdx.x;   // 0..255
    int oy = blockIdx.y;    // 0..255
    int ln = blockIdx.z;
    const float* xn = x + (size_t)(n0 + ln) * 3 * 512 * 512;

    // window as NON-overlapping column pairs: P[ic][r][j] = {col 2j, col 2j+1}
    f32x2 P[3][4][2];
    int iy0 = 2 * oy - 1, ix0 = 2 * ox - 1;

    if (oy > 0 && oy < 255 && ox > 0 && ox < 255) {
#pragma unroll
        for (int ic = 0; ic < 3; ++ic) {
            const float* xc = xn + (size_t)ic * 512 * 512;
#pragma unroll
            for (int r = 0; r < 4; ++r) {
                const float* rp = xc + (size_t)(iy0 + r) * 512 + ix0;
                float a = rp[0];
                float2 m = *(const float2*)(rp + 1);   // cols 1,2 (aligned)
                float b = rp[3];
                P[ic][r][0] = (f32x2){a, m.x};
                P[ic][r][1] = (f32x2){m.y, b};
            }
        }
    } else {
        for (int ic = 0; ic < 3; ++ic) {
            const float* xc = xn + (size_t)ic * 512 * 512;
#pragma unroll
            for (int r = 0; r < 4; ++r) {
                int iy = iy0 + r;
                bool yok = ((unsigned)iy < 512u);
                float t[4];
#pragma unroll
                for (int c = 0; c < 4; ++c) {
                    int ix = ix0 + c;
                    t[c] = (yok && ((unsigned)ix < 512u))
                               ? xc[(size_t)iy * 512 + ix] : 1.0f;
                }
                P[ic][r][0] = (f32x2){t[0], t[1]};
                P[ic][r][1] = (f32x2){t[2], t[3]};
            }
        }
    }

#define PKTAP(ACC, ROW, COL)                                         \
    do {                                                             \
        if (((COL) & 1) == 0) pkfma_lo(ACC, ww, P[ic][ROW][(COL) >> 1]); \
        else                  pkfma_hi(ACC, ww, P[ic][ROW][(COL) >> 1]); \
    } while (0)

    uint64_t dall = 0;
#pragma unroll
    for (int op = 0; op < 4; ++op) {
        f32x2 a00 = {0.f, 0.f}, a01 = {0.f, 0.f};
        f32x2 a10 = {0.f, 0.f}, a11 = {0.f, 0.f};
        const f32x2* wb = w1d + op * 27;
#pragma unroll
        for (int ky = 0; ky < 3; ++ky) {
#pragma unroll
            for (int kx = 0; kx < 3; ++kx) {
#pragma unroll
                for (int ic = 0; ic < 3; ++ic) {
                    f32x2 ww = wb[ic * 9 + ky * 3 + kx];
                    PKTAP(a00, ky + 0, kx + 0);
                    PKTAP(a01, ky + 0, kx + 1);
                    PKTAP(a10, ky + 1, kx + 0);
                    PKTAP(a11, ky + 1, kx + 1);
                }
            }
        }
        float m0 = fmaxf(fmaxf(a00[0], a01[0]), fmaxf(a10[0], a11[0]));
        float m1 = fmaxf(fmaxf(a00[1], a01[1]), fmaxf(a10[1], a11[1]));
        int s0 = (m0 > 0.f) ? 1 : ((m0 < 0.f) ? -1 : 0);
        int s1 = (m1 > 0.f) ? 1 : ((m1 < 0.f) ? -1 : 0);
        dall |= (uint64_t)(uint32_t)(s0 & 0xff) << (8 * (2 * op));
        dall |= (uint64_t)(uint32_t)(s1 & 0xff) << (8 * (2 * op + 1));
    }
#undef PKTAP

    uint32_t d0 = (uint32_t)dall;
    uint32_t d1 = (uint32_t)(dall >> 32);
    size_t base = (((size_t)ln * 2) * 256 + oy) * 256 + ox;
    a1[base]             = d0;
    a1[base + 256 * 256] = d1;
}

// ---- layers 2/3: ternary conv via MFMA i32_32x32x32_i8 -------------------
// R18: operands swapped (weights=A, acts=B) -> C[row=oc, col=px].
// Lane px holds oc = 8g+4h+j at reg 4g+j (h=lane>>5): pack dwords
// in-register, store direct to global. No epilogue LDS.
template<int ICG, int INW, int OUTW, int OCGO>
__global__ __launch_bounds__(256) void kconv(const uint32_t* __restrict__ ain,
                                             const int* __restrict__ wm,
                                             uint32_t* __restrict__ aout) {
    __shared__ uint32_t stb[10][36][4];    // [row][x][icg], rows y0..y0+9
    constexpr int LG = (ICG == 2) ? 1 : 2;
    int w    = threadIdx.x >> 6;
    int lane = threadIdx.x & 63;
    int x0 = blockIdx.x * 32;
    int y0 = blockIdx.y * 8;
    int ln = blockIdx.z;

    const int4v* wmv = (const int4v*)wm;
    int4v bfr[9];
#pragma unroll
    for (int t = 0; t < 9; ++t) bfr[t] = wmv[t * 64 + lane];

    const uint32_t* abase = ain + (size_t)ln * ICG * INW * INW;
    for (int idx = threadIdx.x; idx < 10 * 36 * ICG; idx += 256) {
        int icg = idx & (ICG - 1);
        int r2 = idx >> LG;
        int xx = r2 % 36, row = r2 / 36;
        int gy = y0 + row, gx = x0 + xx;
        uint32_t val = 0;
        if (xx < 34 && gx < INW && gy < INW)
            val = abase[((size_t)icg * INW + gy) * INW + gx];
        stb[row][xx][icg] = val;
    }
    __syncthreads();

    int xl = lane & 31;
    int h  = lane >> 5;

#pragma unroll
    for (int ry = 0; ry < 2; ++ry) {
        int yy = y0 + 2 * w + ry;
        int16v acc = {};
#pragma unroll
        for (int ky = 0; ky < 3; ++ky) {
#pragma unroll
            for (int kx = 0; kx < 3; ++kx) {
                int4v a = *(const int4v*)&stb[2 * w + ry + ky][xl + kx][0];
                // weights as A, activations as B  ->  C[row=oc, col=px]
                acc = __builtin_amdgcn_mfma_i32_32x32x32_i8(bfr[ky * 3 + kx], a, acc, 0, 0, 0);
            }
        }
        bool ok = (yy < OUTW) && (x0 + xl < OUTW);
#pragma unroll
        for (int g = 0; g < 4; ++g) {
            int ocg = 2 * g + h;              // oc = 8g + 4h + j, byte j
            if (ocg < OCGO && ok) {
                uint32_t dw = 0;
#pragma unroll
                for (int j = 0; j < 4; ++j) {
                    int v = min(max(acc[4 * g + j], -1), 1);
                    dw |= (uint32_t)(v & 0xff) << (8 * j);
                }
                aout[(((size_t)ln * OCGO + ocg) * OUTW + yy) * OUTW + x0 + xl] = dw;
            }
        }
    }
}

// ---- layer 4: conv(32->2) ternary, dot4, 2x2 outputs/thread, f32 out -----
__global__ __launch_bounds__(128) void k4(const uint32_t* __restrict__ a3,
                                          const int* __restrict__ w4p,
                                          float* __restrict__ out, int n0) {
    int ox = threadIdx.x; if (ox >= 125) return;
    int oy0 = blockIdx.y * 2;
    int ln = blockIdx.z;

    int acc[2][2][2] = {};
#pragma unroll
    for (int icg = 0; icg < 8; ++icg) {
        uint32_t r[4][4];
        const uint32_t* base = a3 + (((size_t)ln * 8 + icg) * 252 + oy0) * 252 + 2 * ox;
#pragma unroll
        for (int j = 0; j < 4; ++j) {
            uint2 lo = *(const uint2*)(base + (size_t)j * 252);
            uint2 hi = *(const uint2*)(base + (size_t)j * 252 + 2);
            r[j][0] = lo.x; r[j][1] = lo.y; r[j][2] = hi.x; r[j][3] = hi.y;
        }
#pragma unroll
        for (int o = 0; o < 2; ++o) {
            const int* wb = w4p + ((o * 8 + icg) * 9);
#pragma unroll
            for (int ky = 0; ky < 3; ++ky) {
#pragma unroll
                for (int p = 0; p < 2; ++p) {
#pragma unroll
                    for (int q = 0; q < 2; ++q) {
                        acc[p][q][o] = dot4((int)r[p + ky][q + 0], wb[ky * 3 + 0], acc[p][q][o]);
                        acc[p][q][o] = dot4((int)r[p + ky][q + 1], wb[ky * 3 + 1], acc[p][q][o]);
                        acc[p][q][o] = dot4((int)r[p + ky][q + 2], wb[ky * 3 + 2], acc[p][q][o]);
                    }
                }
            }
        }
    }
    size_t gn = (size_t)(n0 + ln);
#pragma unroll
    for (int o = 0; o < 2; ++o)
#pragma unroll
        for (int p = 0; p < 2; ++p) {
            float2 w;
            w.x = fminf(fmaxf((float)acc[p][0][o], -1.f), 1.f);
            w.y = fminf(fmaxf((float)acc[p][1][o], -1.f), 1.f);
            *(float2*)(out + ((gn * 2 + o) * 250 + (oy0 + p)) * 250 + 2 * ox) = w;
        }
}

extern "C" void kernel_launch(void* const* d_in, const int* in_sizes, int n_in,
                              void* d_out, int out_size, void* d_ws, size_t ws_size,
                              hipStream_t stream) {
    const float* x  = (const float*)d_in[0];
    const float* w1 = (const float*)d_in[1];
    const float* w2 = (const float*)d_in[2];
    const float* w3 = (const float*)d_in[3];
    const float* w4 = (const float*)d_in[4];
    char* ws = (char*)d_ws;

    int*   w2m = (int*)(ws + WOFF_W2M);
    int*   w3m = (int*)(ws + WOFF_W3M);
    int*   w4p = (int*)(ws + WOFF_W4P);
    f32x2* w1d = (f32x2*)(ws + WOFF_W1D);
    float* out = (float*)d_out;

    size_t per = (size_t)A1_PB + (size_t)A2_PB + (size_t)A3_PB;
    int NC = 32;
    while (NC > 1 && (size_t)WEIGHTS_BYTES + (size_t)NC * per > ws_size) NC >>= 1;

    uint32_t* A1 = (uint32_t*)(ws + WEIGHTS_BYTES);
    uint32_t* A2 = (uint32_t*)(ws + WEIGHTS_BYTES + (size_t)NC * A1_PB);
    uint32_t* A3 = (uint32_t*)(ws + WEIGHTS_BYTES + (size_t)NC * (A1_PB + A2_PB));

    kprep<<<dim3(3), 256, 0, stream>>>(w1, w2, w3, w4, w2m, w3m, w4p, w1d);
    for (int n0 = 0; n0 < 32; n0 += NC) {
        k1<<<dim3(1, 256, NC), 256, 0, stream>>>(x, w1d, A1, n0);
        kconv<2, 256, 254, 4><<<dim3(8, 32, NC), 256, 0, stream>>>(A1, w2m, A2);
        kconv<4, 254, 252, 8><<<dim3(8, 32, NC), 256, 0, stream>>>(A2, w3m, A3);
        k4<<<dim3(1, 125, NC), 128, 0, stream>>>(A3, w4p, out, n0);
    }
}